// Round 4
// baseline (980.709 us; speedup 1.0000x reference)
//
#include <hip/hip_runtime.h>
#include <math.h>

#define BATCH 4096
#define HID   1024
#define KDIM  1024
#define NSTEP 15
#define KV    3072      // virtual K: [A_hi·B_hi | A_hi·B_lo | A_lo·B_hi]
#define NCHUNK (KV / 64)
#define TAILTHRESH 1536

// Dual-path MFMA GEMM (256 threads = 4 waves, grid 256):
//  count >= TAILTHRESH: cooperative 128x128 block tile, 64x64 per wave
//    (Mf=Nf=4 -> 0.5 LDS reads/MFMA vs 1.0 before), XOR-swizzled LDS
//    (slot ^= row&7 within [row][64-half] tile -> bank-floor reads+writes),
//    double-buffered, depth-2 register prefetch, non-draining barrier.
//  count < TAILTHRESH: per-wave independent 64x64 LDS-free tiles (R3 form,
//    measured ~13us on tails: B panels L2/L3-resident, latency-pipelined).

typedef _Float16 half8 __attribute__((ext_vector_type(8)));
typedef float floatx4 __attribute__((ext_vector_type(4)));

__device__ __forceinline__ _Float16 f16hi(float x) { return (_Float16)x; }

// Barrier that does NOT drain vmcnt: explicit lgkmcnt(0) for LDS visibility.
__device__ __forceinline__ void barrier_ls() {
    asm volatile("s_waitcnt lgkmcnt(0)" ::: "memory");
    __builtin_amdgcn_s_barrier();
    asm volatile("" ::: "memory");
}

// B3[n][kv]: kv<1024: hi(W[n][kv]); 1024..2047: lo; 2048..3071: hi (dup).
// Also: split inputs/hidden into f16 hi/lo, init lists/accums.
__global__ __launch_bounds__(256) void setup_kernel(
    const float* __restrict__ W_ih, const float* __restrict__ W_hh,
    const float* __restrict__ inputs, const float* __restrict__ hidden,
    _Float16* __restrict__ B3ih, _Float16* __restrict__ B3hh,
    _Float16* __restrict__ Ihi, _Float16* __restrict__ Ilo,
    _Float16* __restrict__ Hhi, _Float16* __restrict__ Hlo,
    float* __restrict__ flagcol, int* __restrict__ list0, int* __restrict__ counts,
    float* __restrict__ halt_accum, float* __restrict__ tot_rem) {
    size_t idx = (size_t)blockIdx.x * 256 + threadIdx.x;   // grid 16384 -> 4M
    {   // split inputs -> I, hidden -> H
        float x = inputs[idx];
        _Float16 h = f16hi(x);
        Ihi[idx] = h; Ilo[idx] = (_Float16)(x - (float)h);
        float y = hidden[idx];
        _Float16 g = f16hi(y);
        Hhi[idx] = g; Hlo[idx] = (_Float16)(y - (float)g);
    }
    if (idx < (size_t)KDIM * KDIM) {
        int n = (int)(idx >> 10), k = (int)(idx & 1023);
        float w = W_hh[idx];
        _Float16 hi = f16hi(w);
        _Float16 lo = (_Float16)(w - (float)hi);
        size_t base = (size_t)n * KV;
        B3hh[base + k] = hi; B3hh[base + 1024 + k] = lo; B3hh[base + 2048 + k] = hi;
        float w2 = W_ih[(size_t)n * 1025 + k];
        _Float16 hi2 = f16hi(w2);
        _Float16 lo2 = (_Float16)(w2 - (float)hi2);
        B3ih[base + k] = hi2; B3ih[base + 1024 + k] = lo2; B3ih[base + 2048 + k] = hi2;
    }
    if (idx < BATCH) { list0[idx] = idx; halt_accum[idx] = 0.f; tot_rem[idx] = 0.f; }
    if (idx < KDIM) flagcol[idx] = W_ih[idx * 1025 + 1024];
    if (idx < 16) counts[idx] = (idx == 0) ? BATCH : 0;
}

// mode 0: xout[row] = A @ B^T + bias (fp32)
// mode 1: h = tanh(acc + xbase + flag*flagcol + bias); store h fp32 + hi/lo f16
__global__ __launch_bounds__(256, 1) void mfma_step_kernel(
    const _Float16* __restrict__ Ahi, const _Float16* __restrict__ Alo,
    const _Float16* __restrict__ B3, const float* __restrict__ bias,
    const float* __restrict__ xbase, const float* __restrict__ flagcol, float flag,
    const int* __restrict__ list, const int* __restrict__ pcount,
    float* __restrict__ hout, _Float16* __restrict__ houthi, _Float16* __restrict__ houtlo,
    float* __restrict__ xout, int mode) {
    int count = pcount ? *pcount : BATCH;
    int t = threadIdx.x;
    int lane = t & 63, w = t >> 6;
    int l15 = lane & 15, l4 = lane >> 4;

    __shared__ _Float16 sm[2][2][128 * 64];   // [buf][A/B][row*64 + swz-col]

    if (count >= TAILTHRESH) {
        // ================= full path: 128x128 cooperative =================
        int bx = blockIdx.x >> 3, by = blockIdx.x & 7;     // 32 x 8
        int row0 = bx * 128;
        if (row0 >= count) return;                          // block-uniform
        int col0 = by * 128;
        int wm = (w & 1) * 64, wn = (w >> 1) * 64;

        // staging: 4 A-quads + 4 B-quads per thread (1024 quads each tile)
        size_t aoff[4], boff[4]; int aldso[4], bldso[4];
#pragma unroll
        for (int i = 0; i < 4; i++) {
            int q = t + i * 256;
            int r = q >> 3, qk = q & 7;
            int grow = row0 + r;
            int g = (grow < count) ? (list ? list[grow] : grow) : 0;
            aoff[i] = (size_t)g * KDIM + qk * 8;
            boff[i] = (size_t)(col0 + r) * KV + qk * 8;
            int so = r * 64 + ((qk ^ (r & 7)) << 3);        // swizzled half-idx
            aldso[i] = so; bldso[i] = so;
        }

        // fragment read offsets (halfs): row = wm/wn + fi*16 + l15
        int sw = l15 & 7;
        int sA[2], rofA[4], rofB[4];
#pragma unroll
        for (int ks = 0; ks < 2; ks++) sA[ks] = ((ks * 4 + l4) ^ sw) << 3;
#pragma unroll
        for (int f = 0; f < 4; f++) {
            rofA[f] = (wm + f * 16 + l15) * 64;
            rofB[f] = (wn + f * 16 + l15) * 64;
        }

        floatx4 acc[4][4];
#pragma unroll
        for (int i = 0; i < 4; i++)
#pragma unroll
            for (int j = 0; j < 4; j++) acc[i][j] = (floatx4)(0.f);

        half8 avE[4], bvE[4], avO[4], bvO[4];

#define ISSUE(avS, bvS, c) do {                                               \
        int k0v_ = (c) << 6;                                                  \
        const _Float16* As_ = (k0v_ < 2048) ? Ahi : Alo; /* segs [hi,hi,lo] */ \
        int kp_ = k0v_ & 1023;                                                \
        _Pragma("unroll")                                                     \
        for (int i = 0; i < 4; i++) {                                         \
            avS[i] = *(const half8*)(As_ + aoff[i] + kp_);                    \
            bvS[i] = *(const half8*)(B3 + boff[i] + k0v_);                    \
        }                                                                     \
    } while (0)

#define LDSW(buf, avS, bvS) do {                                              \
        _Pragma("unroll")                                                     \
        for (int i = 0; i < 4; i++) {                                         \
            *(half8*)(&sm[buf][0][aldso[i]]) = avS[i];                        \
            *(half8*)(&sm[buf][1][bldso[i]]) = bvS[i];                        \
        }                                                                     \
    } while (0)

#define MFMA_CHUNK(buf) do {                                                  \
        _Pragma("unroll")                                                     \
        for (int ks = 0; ks < 2; ks++) {                                      \
            half8 af[4], bf[4];                                               \
            _Pragma("unroll")                                                 \
            for (int f = 0; f < 4; f++) {                                     \
                af[f] = *(const half8*)(&sm[buf][0][rofA[f] + sA[ks]]);       \
                bf[f] = *(const half8*)(&sm[buf][1][rofB[f] + sA[ks]]);       \
            }                                                                 \
            _Pragma("unroll")                                                 \
            for (int fi = 0; fi < 4; fi++)                                    \
                _Pragma("unroll")                                             \
                for (int fj = 0; fj < 4; fj++)                                \
                    acc[fi][fj] = __builtin_amdgcn_mfma_f32_16x16x32_f16(     \
                        af[fi], bf[fj], acc[fi][fj], 0, 0, 0);                \
        }                                                                     \
    } while (0)

        ISSUE(avE, bvE, 0);
        ISSUE(avO, bvO, 1);
        LDSW(0, avE, bvE);
        barrier_ls();

        for (int it = 0; it < NCHUNK; it += 2) {
            if (it + 2 < NCHUNK) ISSUE(avE, bvE, it + 2);
            MFMA_CHUNK(0);
            LDSW(1, avO, bvO);
            barrier_ls();
            if (it + 3 < NCHUNK) ISSUE(avO, bvO, it + 3);
            MFMA_CHUNK(1);
            if (it + 2 < NCHUNK) LDSW(0, avE, bvE);
            barrier_ls();
        }
#undef ISSUE
#undef LDSW
#undef MFMA_CHUNK

        // epilogue: col = lane&15, row = (lane>>4)*4 + reg  [m89-verified]
#pragma unroll
        for (int fi = 0; fi < 4; fi++) {
#pragma unroll
            for (int rr = 0; rr < 4; rr++) {
                int lm = wm + fi * 16 + l4 * 4 + rr;
                int grd = row0 + lm;
                if (grd >= count) continue;
                int g = list ? list[grd] : grd;
#pragma unroll
                for (int fj = 0; fj < 4; fj++) {
                    int c = col0 + wn + fj * 16 + l15;
                    float v = acc[fi][fj][rr];
                    if (mode == 0) {
                        xout[(size_t)g * KDIM + c] = v + bias[c];
                    } else {
                        v += xbase[(size_t)g * KDIM + c] + flag * flagcol[c] + bias[c];
                        v = tanhf(v);
                        hout[(size_t)g * KDIM + c] = v;
                        _Float16 hi = f16hi(v);
                        houthi[(size_t)g * KDIM + c] = hi;
                        houtlo[(size_t)g * KDIM + c] = (_Float16)(v - (float)hi);
                    }
                }
            }
        }
    } else {
        // ============ tail path: per-wave 64x64, LDS-free (R3) ============
        int tid = blockIdx.x * 4 + w;                       // 0..1023
        int bx = tid >> 4, by = tid & 15;
        int row0 = bx * 64;
        if (row0 >= count) return;                          // per-wave exit ok
        int col0 = by * 64;
        int koff = l4 * 8;

        size_t abase[4], bbase[4];
#pragma unroll
        for (int f = 0; f < 4; f++) {
            int grow = row0 + f * 16 + l15;
            int g = (grow < count) ? (list ? list[grow] : grow) : 0;
            abase[f] = (size_t)g * KDIM + koff;
            bbase[f] = (size_t)(col0 + f * 16 + l15) * KV + koff;
        }

        floatx4 acc[4][4];
#pragma unroll
        for (int i = 0; i < 4; i++)
#pragma unroll
            for (int j = 0; j < 4; j++) acc[i][j] = (floatx4)(0.f);

        half8 avA[4][2], bvA[4][2], avB[4][2], bvB[4][2], avC[4][2], bvC[4][2];

#define TISSUE(av, bv, c) do {                                                \
        int k0v_ = (c) << 6;                                                  \
        const _Float16* As_ = (k0v_ < 2048) ? Ahi : Alo;                      \
        int kp_ = k0v_ & 1023;                                                \
        _Pragma("unroll")                                                     \
        for (int f = 0; f < 4; f++) {                                         \
            _Pragma("unroll")                                                 \
            for (int ks = 0; ks < 2; ks++) {                                  \
                av[f][ks] = *(const half8*)(As_ + abase[f] + kp_ + ks * 32);  \
                bv[f][ks] = *(const half8*)(B3 + bbase[f] + k0v_ + ks * 32);  \
            }                                                                 \
        }                                                                     \
    } while (0)

#define TMFMA(av, bv) do {                                                    \
        _Pragma("unroll")                                                     \
        for (int ks = 0; ks < 2; ks++)                                        \
            _Pragma("unroll")                                                 \
            for (int fi = 0; fi < 4; fi++)                                    \
                _Pragma("unroll")                                             \
                for (int fj = 0; fj < 4; fj++)                                \
                    acc[fi][fj] = __builtin_amdgcn_mfma_f32_16x16x32_f16(     \
                        av[fi][ks], bv[fj][ks], acc[fi][fj], 0, 0, 0);        \
    } while (0)

        TISSUE(avA, bvA, 0);
        TISSUE(avB, bvB, 1);
        TISSUE(avC, bvC, 2);

        for (int it = 0; it < NCHUNK; it += 3) {
            TMFMA(avA, bvA);
            if (it + 3 < NCHUNK) TISSUE(avA, bvA, it + 3);
            TMFMA(avB, bvB);
            if (it + 4 < NCHUNK) TISSUE(avB, bvB, it + 4);
            TMFMA(avC, bvC);
            if (it + 5 < NCHUNK) TISSUE(avC, bvC, it + 5);
        }
#undef TISSUE
#undef TMFMA

#pragma unroll
        for (int fi = 0; fi < 4; fi++) {
#pragma unroll
            for (int rr = 0; rr < 4; rr++) {
                int lm = fi * 16 + l4 * 4 + rr;
                int grd = row0 + lm;
                if (grd >= count) continue;
                int g = list ? list[grd] : grd;
#pragma unroll
                for (int fj = 0; fj < 4; fj++) {
                    int c = col0 + fj * 16 + l15;
                    float v = acc[fi][fj][rr];
                    if (mode == 0) {
                        xout[(size_t)g * KDIM + c] = v + bias[c];
                    } else {
                        v += xbase[(size_t)g * KDIM + c] + flag * flagcol[c] + bias[c];
                        v = tanhf(v);
                        hout[(size_t)g * KDIM + c] = v;
                        _Float16 hi = f16hi(v);
                        houthi[(size_t)g * KDIM + c] = hi;
                        houtlo[(size_t)g * KDIM + c] = (_Float16)(v - (float)hi);
                    }
                }
            }
        }
    }
}

// One wave per active row: halt logit, sigmoid, halting state machine,
// tot_h accumulation into d_out, compaction of next-step list.  (R1-verified)
__global__ __launch_bounds__(256) void halt_kernel(
    const float* __restrict__ h, const float* __restrict__ W_halt,
    const float* __restrict__ b_halt,
    const int* __restrict__ list, const int* __restrict__ pcount,
    int* __restrict__ list_next, int* __restrict__ pcount_next,
    float* __restrict__ halt_accum, float* __restrict__ tot_rem,
    float* __restrict__ tot_h, float* __restrict__ steps_out,
    int stepnum, int first) {
    int count = *pcount;
    int wid = threadIdx.x >> 6, lane = threadIdx.x & 63;
    int r = blockIdx.x * 4 + wid;
    if (r >= count) return;
    int row = list[r];
    const float* hr = h + (size_t)row * HID;

    float dot = 0.f;
#pragma unroll
    for (int q = 0; q < 4; q++) {
        int c = q * 256 + lane * 4;
        float4 hv = *(const float4*)(hr + c);
        float4 wv = *(const float4*)(W_halt + c);
        dot += hv.x * wv.x + hv.y * wv.y + hv.z * wv.z + hv.w * wv.w;
    }
#pragma unroll
    for (int off = 32; off > 0; off >>= 1) dot += __shfl_down(dot, off);

    float combined = 0.f;
    if (lane == 0) {
        float p = 1.f / (1.f + expf(-(dot + b_halt[0])));
        float S = halt_accum[row] + p;
        halt_accum[row] = S;
        tot_rem[row] += p;
        bool ending = (S + p) > 0.99f;      // budget = 1 - PONDER_EPS
        if (ending) {
            combined = p + (1.f - S);
            steps_out[row] = (float)stepnum;
        } else {
            combined = p;
            int idx = atomicAdd(pcount_next, 1);
            list_next[idx] = row;
        }
    }
    combined = __shfl(combined, 0);

    float* th = tot_h + (size_t)row * HID;
#pragma unroll
    for (int q = 0; q < 4; q++) {
        int c = q * 256 + lane * 4;
        float4 hv = *(const float4*)(hr + c);
        float4 ov;
        if (first) {
            ov.x = combined * hv.x; ov.y = combined * hv.y;
            ov.z = combined * hv.z; ov.w = combined * hv.w;
        } else {
            ov = *(const float4*)(th + c);
            ov.x += combined * hv.x; ov.y += combined * hv.y;
            ov.z += combined * hv.z; ov.w += combined * hv.w;
        }
        *(float4*)(th + c) = ov;
    }
}

// blocks 0..1023: survivors get (1 - halt_accum) * h_final, steps = 16.
// block 1024: ponder reduction.
__global__ __launch_bounds__(256) void epilogue_kernel(
    const float* __restrict__ h, const int* __restrict__ list,
    const int* __restrict__ pcount, const float* __restrict__ halt_accum,
    const float* __restrict__ tot_rem,
    float* __restrict__ tot_h, float* __restrict__ steps_out,
    float* __restrict__ ponder) {
    if (blockIdx.x == 1024) {
        __shared__ float red[4];
        int t = threadIdx.x;
        float v = 0.f;
#pragma unroll
        for (int i = 0; i < 16; i++) v += tot_rem[t + i * 256];
#pragma unroll
        for (int off = 32; off > 0; off >>= 1) v += __shfl_down(v, off);
        int lane = t & 63, wid = t >> 6;
        if (lane == 0) red[wid] = v;
        __syncthreads();
        if (t == 0) ponder[0] = (red[0] + red[1] + red[2] + red[3]) * (-0.01f / 4096.f);
        return;
    }
    int count = *pcount;
    int wid = threadIdx.x >> 6, lane = threadIdx.x & 63;
    int r = blockIdx.x * 4 + wid;
    if (r >= count) return;
    int row = list[r];
    float cmb = 1.f - halt_accum[row];
    if (lane == 0) steps_out[row] = 16.f;
    const float* hr = h + (size_t)row * HID;
    float* th = tot_h + (size_t)row * HID;
#pragma unroll
    for (int q = 0; q < 4; q++) {
        int c = q * 256 + lane * 4;
        float4 hv = *(const float4*)(hr + c);
        float4 ov = *(const float4*)(th + c);
        ov.x += cmb * hv.x; ov.y += cmb * hv.y;
        ov.z += cmb * hv.z; ov.w += cmb * hv.w;
        *(float4*)(th + c) = ov;
    }
}

extern "C" void kernel_launch(void* const* d_in, const int* in_sizes, int n_in,
                              void* d_out, int out_size, void* d_ws, size_t ws_size,
                              hipStream_t stream) {
    const float* inputs = (const float*)d_in[0];
    const float* hidden = (const float*)d_in[1];
    const float* W_ih   = (const float*)d_in[2];
    const float* b_ih   = (const float*)d_in[3];
    const float* W_hh   = (const float*)d_in[4];
    const float* b_hh   = (const float*)d_in[5];
    const float* W_halt = (const float*)d_in[6];
    const float* b_halt = (const float*)d_in[7];
    float* out = (float*)d_out;

    float* ws = (float*)d_ws;
    const size_t NM = (size_t)BATCH * HID;               // 4M
    float* xbase = ws;                                   // 4M f32
    float* h     = xbase + NM;                           // 4M f32
    _Float16* B3ih = (_Float16*)(h + NM);                // 1024*3072 halfs
    _Float16* B3hh = B3ih + (size_t)HID * KV;
    _Float16* Ahi0 = B3hh + (size_t)HID * KV;            // 4M halfs each
    _Float16* Alo0 = Ahi0 + NM;
    _Float16* Ahi1 = Alo0 + NM;
    _Float16* Alo1 = Ahi1 + NM;
    float* flagcol = (float*)(Alo1 + NM);                // 1024
    float* halt_accum = flagcol + KDIM;                  // 4096
    float* tot_rem = halt_accum + BATCH;                 // 4096
    int* list0 = (int*)(tot_rem + BATCH);                // 4096
    int* list1 = list0 + BATCH;                          // 4096
    int* counts = list1 + BATCH;                         // 16

    _Float16* Ahi[2] = {Ahi0, Ahi1};
    _Float16* Alo[2] = {Alo0, Alo1};
    int* lists[2] = {list0, list1};

    float* tot_h = out;
    float* ponder = out + NM;
    float* steps_out = ponder + 1;

    // setup + split fused: inputs -> buf1 (dead after x_base), hidden -> buf0
    setup_kernel<<<16384, 256, 0, stream>>>(W_ih, W_hh, inputs, hidden,
                                            B3ih, B3hh, Ahi1, Alo1, Ahi0, Alo0,
                                            flagcol, list0, counts, halt_accum, tot_rem);

    // x_base = inputs @ W_ih[:, :-1].T + b_ih
    mfma_step_kernel<<<256, 256, 0, stream>>>(
        Ahi1, Alo1, B3ih, b_ih, nullptr, nullptr, 0.f, nullptr, nullptr,
        nullptr, nullptr, nullptr, xbase, 0);

    for (int t = 0; t < NSTEP; t++) {
        mfma_step_kernel<<<256, 256, 0, stream>>>(
            Ahi[t & 1], Alo[t & 1], B3hh, b_hh, xbase, flagcol,
            (t == 0) ? 1.f : 0.f, lists[t & 1], counts + t,
            h, Ahi[(t + 1) & 1], Alo[(t + 1) & 1], nullptr, 1);
        halt_kernel<<<1024, 256, 0, stream>>>(h, W_halt, b_halt,
                                              lists[t & 1], counts + t,
                                              lists[(t + 1) & 1], counts + t + 1,
                                              halt_accum, tot_rem, tot_h, steps_out,
                                              t + 1, (t == 0) ? 1 : 0);
    }
    epilogue_kernel<<<1025, 256, 0, stream>>>(h, lists[1], counts + 15,
                                              halt_accum, tot_rem, tot_h, steps_out, ponder);
}

// Round 5
// 909.907 us; speedup vs baseline: 1.0778x; 1.0778x over previous
//
#include <hip/hip_runtime.h>
#include <math.h>

#define BATCH 4096
#define HID   1024
#define KDIM  1024
#define NSTEP 15
#define KV    3072      // virtual K: [A_hi·B_hi | A_hi·B_lo | A_lo·B_hi]
#define NCHUNK (KV / 64)
#define TAILTHRESH 1536

// Dual-path MFMA GEMM, grid 512 x 256 threads, block-uniform path select:
//  count >= TAILTHRESH: R0-verified cooperative path (63.4us measured):
//    128(M) x 64(N) block tile, 4 waves (wave 64x32, frags 4x2), LDS double
//    buffer with +8-half pad (LDAH=72), register prefetch, __syncthreads.
//  count < TAILTHRESH: R3-verified LDS-free path: per-WAVE independent 64x64
//    tiles, fragments gathered from global (B panels L2/L3-resident at small
//    count), depth-3 register pipeline. Tile id = w*512 + blockIdx.x so the
//    <=384 active tiles land in DISTINCT blocks (R4 lesson: packing 4 tiles
//    per block concentrated work on 96 CUs -> 118us; spreading -> ~10us).
#define TMM 128
#define TNN 64
#define LDAH 72         // LDS row stride in halfs (144B)

typedef _Float16 half8 __attribute__((ext_vector_type(8)));
typedef float floatx4 __attribute__((ext_vector_type(4)));

__device__ __forceinline__ _Float16 f16hi(float x) { return (_Float16)x; }

// B3[n][kv]: kv<1024: hi(W[n][kv]); 1024..2047: lo; 2048..3071: hi (dup).
// Also: split inputs/hidden into f16 hi/lo, init lists/accums.
__global__ __launch_bounds__(256) void setup_kernel(
    const float* __restrict__ W_ih, const float* __restrict__ W_hh,
    const float* __restrict__ inputs, const float* __restrict__ hidden,
    _Float16* __restrict__ B3ih, _Float16* __restrict__ B3hh,
    _Float16* __restrict__ Ihi, _Float16* __restrict__ Ilo,
    _Float16* __restrict__ Hhi, _Float16* __restrict__ Hlo,
    float* __restrict__ flagcol, int* __restrict__ list0, int* __restrict__ counts,
    float* __restrict__ halt_accum, float* __restrict__ tot_rem) {
    size_t idx = (size_t)blockIdx.x * 256 + threadIdx.x;   // grid 16384 -> 4M
    {   // split inputs -> I, hidden -> H
        float x = inputs[idx];
        _Float16 h = f16hi(x);
        Ihi[idx] = h; Ilo[idx] = (_Float16)(x - (float)h);
        float y = hidden[idx];
        _Float16 g = f16hi(y);
        Hhi[idx] = g; Hlo[idx] = (_Float16)(y - (float)g);
    }
    if (idx < (size_t)KDIM * KDIM) {
        int n = (int)(idx >> 10), k = (int)(idx & 1023);
        float w = W_hh[idx];
        _Float16 hi = f16hi(w);
        _Float16 lo = (_Float16)(w - (float)hi);
        size_t base = (size_t)n * KV;
        B3hh[base + k] = hi; B3hh[base + 1024 + k] = lo; B3hh[base + 2048 + k] = hi;
        float w2 = W_ih[(size_t)n * 1025 + k];
        _Float16 hi2 = f16hi(w2);
        _Float16 lo2 = (_Float16)(w2 - (float)hi2);
        B3ih[base + k] = hi2; B3ih[base + 1024 + k] = lo2; B3ih[base + 2048 + k] = hi2;
    }
    if (idx < BATCH) { list0[idx] = idx; halt_accum[idx] = 0.f; tot_rem[idx] = 0.f; }
    if (idx < KDIM) flagcol[idx] = W_ih[idx * 1025 + 1024];
    if (idx < 16) counts[idx] = (idx == 0) ? BATCH : 0;
}

// mode 0: xout[row] = A @ B^T + bias (fp32)
// mode 1: h = tanh(acc + xbase + flag*flagcol + bias); store h fp32 + hi/lo f16
__global__ __launch_bounds__(256) void mfma_step_kernel(
    const _Float16* __restrict__ Ahi, const _Float16* __restrict__ Alo,
    const _Float16* __restrict__ B3, const float* __restrict__ bias,
    const float* __restrict__ xbase, const float* __restrict__ flagcol, float flag,
    const int* __restrict__ list, const int* __restrict__ pcount,
    float* __restrict__ hout, _Float16* __restrict__ houthi, _Float16* __restrict__ houtlo,
    float* __restrict__ xout, int mode) {
    int count = pcount ? *pcount : BATCH;
    int t = threadIdx.x;
    int lane = t & 63, w = t >> 6;
    int l15 = lane & 15, l4 = lane >> 4;

    __shared__ _Float16 Asm[2][TMM][LDAH];
    __shared__ _Float16 Bsm[2][TNN][LDAH];

    if (count >= TAILTHRESH) {
        // ============ full path: R0-verified 128x64 cooperative ============
        int bx = blockIdx.x & 31, by = blockIdx.x >> 5;    // 32 x 16
        int row0 = bx * TMM;
        if (row0 >= count) return;                          // block-uniform
        int col0 = by * TNN;
        int wm = (w & 1) * 64, wn = (w >> 1) * 32;

        // A staging: 128 rows x 8 half8-quads = 1024 quads, 4/thread
        int arw[4], aq8[4]; size_t aoff[4];
#pragma unroll
        for (int l = 0; l < 4; l++) {
            int q = t + l * 256;
            int r = q >> 3, qk = q & 7;
            arw[l] = r; aq8[l] = qk * 8;
            int rr = row0 + r;
            int g = (rr < count) ? (list ? list[rr] : rr) : 0;
            aoff[l] = (size_t)g * KDIM + qk * 8;
        }
        // B staging: 64 n-rows x 8 quads = 512 quads, 2/thread
        int brw[2], bq8[2]; size_t boff[2];
#pragma unroll
        for (int l = 0; l < 2; l++) {
            int q = t + l * 256;
            int r = q >> 3, qk = q & 7;
            brw[l] = r; bq8[l] = qk * 8;
            boff[l] = (size_t)(col0 + r) * KV + qk * 8;
        }

        floatx4 acc[4][2];
#pragma unroll
        for (int i = 0; i < 4; i++)
#pragma unroll
            for (int j = 0; j < 2; j++) acc[i][j] = (floatx4)(0.f);

        // preload chunk 0 into buf 0
        half8 av[4], bv[2];
#pragma unroll
        for (int l = 0; l < 4; l++) av[l] = *(const half8*)(Ahi + aoff[l]);
#pragma unroll
        for (int l = 0; l < 2; l++) bv[l] = *(const half8*)(B3 + boff[l]);
#pragma unroll
        for (int l = 0; l < 4; l++) *(half8*)(&Asm[0][arw[l]][aq8[l]]) = av[l];
#pragma unroll
        for (int l = 0; l < 2; l++) *(half8*)(&Bsm[0][brw[l]][bq8[l]]) = bv[l];
        __syncthreads();

        int p = 0;
        for (int it = 0; it < NCHUNK; it++) {
            if (it + 1 < NCHUNK) {          // prefetch chunk it+1
                int k0v = (it + 1) << 6;
                const _Float16* Asrc = (k0v < 2048) ? Ahi : Alo;
                int kp = k0v & 1023;
#pragma unroll
                for (int l = 0; l < 4; l++) av[l] = *(const half8*)(Asrc + aoff[l] + kp);
#pragma unroll
                for (int l = 0; l < 2; l++) bv[l] = *(const half8*)(B3 + boff[l] + k0v);
            }
#pragma unroll
            for (int ks = 0; ks < 2; ks++) {
                int ko = ks * 32 + l4 * 8;
                half8 af[4], bf[2];
#pragma unroll
                for (int fi = 0; fi < 4; fi++)
                    af[fi] = *(const half8*)(&Asm[p][wm + fi * 16 + l15][ko]);
#pragma unroll
                for (int fj = 0; fj < 2; fj++)
                    bf[fj] = *(const half8*)(&Bsm[p][wn + fj * 16 + l15][ko]);
#pragma unroll
                for (int fi = 0; fi < 4; fi++)
#pragma unroll
                    for (int fj = 0; fj < 2; fj++)
                        acc[fi][fj] = __builtin_amdgcn_mfma_f32_16x16x32_f16(
                            af[fi], bf[fj], acc[fi][fj], 0, 0, 0);
            }
            if (it + 1 < NCHUNK) {
                int q = p ^ 1;
#pragma unroll
                for (int l = 0; l < 4; l++) *(half8*)(&Asm[q][arw[l]][aq8[l]]) = av[l];
#pragma unroll
                for (int l = 0; l < 2; l++) *(half8*)(&Bsm[q][brw[l]][bq8[l]]) = bv[l];
            }
            __syncthreads();
            p ^= 1;
        }

        // epilogue: col = lane&15, row = (lane>>4)*4 + reg  [m89-verified]
#pragma unroll
        for (int fi = 0; fi < 4; fi++) {
#pragma unroll
            for (int rr = 0; rr < 4; rr++) {
                int lm = wm + fi * 16 + l4 * 4 + rr;
                int grd = row0 + lm;
                if (grd >= count) continue;
                int g = list ? list[grd] : grd;
#pragma unroll
                for (int fj = 0; fj < 2; fj++) {
                    int c = col0 + wn + fj * 16 + l15;
                    float v = acc[fi][fj][rr];
                    if (mode == 0) {
                        xout[(size_t)g * KDIM + c] = v + bias[c];
                    } else {
                        v += xbase[(size_t)g * KDIM + c] + flag * flagcol[c] + bias[c];
                        v = tanhf(v);
                        hout[(size_t)g * KDIM + c] = v;
                        _Float16 hi = f16hi(v);
                        houthi[(size_t)g * KDIM + c] = hi;
                        houtlo[(size_t)g * KDIM + c] = (_Float16)(v - (float)hi);
                    }
                }
            }
        }
    } else {
        // ============ tail path: per-wave 64x64, LDS-free (R3) ============
        // Spread: tile id = w*512 + blockIdx.x -> active ids (< 24*16=384 for
        // count<1536) land in distinct blocks, 1 working wave per block.
        int tid = w * 512 + blockIdx.x;
        int bx = tid >> 4, by = tid & 15;
        int row0 = bx * 64;
        if (row0 >= count) return;          // per-wave exit (no barriers here)
        int col0 = by * 64;
        int koff = l4 * 8;

        size_t abase[4], bbase[4];
#pragma unroll
        for (int f = 0; f < 4; f++) {
            int grow = row0 + f * 16 + l15;
            int g = (grow < count) ? (list ? list[grow] : grow) : 0;
            abase[f] = (size_t)g * KDIM + koff;
            bbase[f] = (size_t)(col0 + f * 16 + l15) * KV + koff;
        }

        floatx4 acc[4][4];
#pragma unroll
        for (int i = 0; i < 4; i++)
#pragma unroll
            for (int j = 0; j < 4; j++) acc[i][j] = (floatx4)(0.f);

        half8 avA[4][2], bvA[4][2], avB[4][2], bvB[4][2], avC[4][2], bvC[4][2];

#define TISSUE(av, bv, c) do {                                                \
        int k0v_ = (c) << 6;                                                  \
        const _Float16* As_ = (k0v_ < 2048) ? Ahi : Alo;                      \
        int kp_ = k0v_ & 1023;                                                \
        _Pragma("unroll")                                                     \
        for (int f = 0; f < 4; f++) {                                         \
            _Pragma("unroll")                                                 \
            for (int ks = 0; ks < 2; ks++) {                                  \
                av[f][ks] = *(const half8*)(As_ + abase[f] + kp_ + ks * 32);  \
                bv[f][ks] = *(const half8*)(B3 + bbase[f] + k0v_ + ks * 32);  \
            }                                                                 \
        }                                                                     \
    } while (0)

#define TMFMA(av, bv) do {                                                    \
        _Pragma("unroll")                                                     \
        for (int ks = 0; ks < 2; ks++)                                        \
            _Pragma("unroll")                                                 \
            for (int fi = 0; fi < 4; fi++)                                    \
                _Pragma("unroll")                                             \
                for (int fj = 0; fj < 4; fj++)                                \
                    acc[fi][fj] = __builtin_amdgcn_mfma_f32_16x16x32_f16(     \
                        av[fi][ks], bv[fj][ks], acc[fi][fj], 0, 0, 0);        \
    } while (0)

        TISSUE(avA, bvA, 0);
        TISSUE(avB, bvB, 1);
        TISSUE(avC, bvC, 2);

        for (int it = 0; it < NCHUNK; it += 3) {
            TMFMA(avA, bvA);
            if (it + 3 < NCHUNK) TISSUE(avA, bvA, it + 3);
            TMFMA(avB, bvB);
            if (it + 4 < NCHUNK) TISSUE(avB, bvB, it + 4);
            TMFMA(avC, bvC);
            if (it + 5 < NCHUNK) TISSUE(avC, bvC, it + 5);
        }
#undef TISSUE
#undef TMFMA

#pragma unroll
        for (int fi = 0; fi < 4; fi++) {
#pragma unroll
            for (int rr = 0; rr < 4; rr++) {
                int lm = fi * 16 + l4 * 4 + rr;
                int grd = row0 + lm;
                if (grd >= count) continue;
                int g = list ? list[grd] : grd;
#pragma unroll
                for (int fj = 0; fj < 4; fj++) {
                    int c = col0 + fj * 16 + l15;
                    float v = acc[fi][fj][rr];
                    if (mode == 0) {
                        xout[(size_t)g * KDIM + c] = v + bias[c];
                    } else {
                        v += xbase[(size_t)g * KDIM + c] + flag * flagcol[c] + bias[c];
                        v = tanhf(v);
                        hout[(size_t)g * KDIM + c] = v;
                        _Float16 hi = f16hi(v);
                        houthi[(size_t)g * KDIM + c] = hi;
                        houtlo[(size_t)g * KDIM + c] = (_Float16)(v - (float)hi);
                    }
                }
            }
        }
    }
}

// One wave per active row: halt logit, sigmoid, halting state machine,
// tot_h accumulation into d_out, compaction of next-step list.  (R1-verified)
__global__ __launch_bounds__(256) void halt_kernel(
    const float* __restrict__ h, const float* __restrict__ W_halt,
    const float* __restrict__ b_halt,
    const int* __restrict__ list, const int* __restrict__ pcount,
    int* __restrict__ list_next, int* __restrict__ pcount_next,
    float* __restrict__ halt_accum, float* __restrict__ tot_rem,
    float* __restrict__ tot_h, float* __restrict__ steps_out,
    int stepnum, int first) {
    int count = *pcount;
    int wid = threadIdx.x >> 6, lane = threadIdx.x & 63;
    int r = blockIdx.x * 4 + wid;
    if (r >= count) return;
    int row = list[r];
    const float* hr = h + (size_t)row * HID;

    float dot = 0.f;
#pragma unroll
    for (int q = 0; q < 4; q++) {
        int c = q * 256 + lane * 4;
        float4 hv = *(const float4*)(hr + c);
        float4 wv = *(const float4*)(W_halt + c);
        dot += hv.x * wv.x + hv.y * wv.y + hv.z * wv.z + hv.w * wv.w;
    }
#pragma unroll
    for (int off = 32; off > 0; off >>= 1) dot += __shfl_down(dot, off);

    float combined = 0.f;
    if (lane == 0) {
        float p = 1.f / (1.f + expf(-(dot + b_halt[0])));
        float S = halt_accum[row] + p;
        halt_accum[row] = S;
        tot_rem[row] += p;
        bool ending = (S + p) > 0.99f;      // budget = 1 - PONDER_EPS
        if (ending) {
            combined = p + (1.f - S);
            steps_out[row] = (float)stepnum;
        } else {
            combined = p;
            int idx = atomicAdd(pcount_next, 1);
            list_next[idx] = row;
        }
    }
    combined = __shfl(combined, 0);

    float* th = tot_h + (size_t)row * HID;
#pragma unroll
    for (int q = 0; q < 4; q++) {
        int c = q * 256 + lane * 4;
        float4 hv = *(const float4*)(hr + c);
        float4 ov;
        if (first) {
            ov.x = combined * hv.x; ov.y = combined * hv.y;
            ov.z = combined * hv.z; ov.w = combined * hv.w;
        } else {
            ov = *(const float4*)(th + c);
            ov.x += combined * hv.x; ov.y += combined * hv.y;
            ov.z += combined * hv.z; ov.w += combined * hv.w;
        }
        *(float4*)(th + c) = ov;
    }
}

// blocks 0..1023: survivors get (1 - halt_accum) * h_final, steps = 16.
// block 1024: ponder reduction.
__global__ __launch_bounds__(256) void epilogue_kernel(
    const float* __restrict__ h, const int* __restrict__ list,
    const int* __restrict__ pcount, const float* __restrict__ halt_accum,
    const float* __restrict__ tot_rem,
    float* __restrict__ tot_h, float* __restrict__ steps_out,
    float* __restrict__ ponder) {
    if (blockIdx.x == 1024) {
        __shared__ float red[4];
        int t = threadIdx.x;
        float v = 0.f;
#pragma unroll
        for (int i = 0; i < 16; i++) v += tot_rem[t + i * 256];
#pragma unroll
        for (int off = 32; off > 0; off >>= 1) v += __shfl_down(v, off);
        int lane = t & 63, wid = t >> 6;
        if (lane == 0) red[wid] = v;
        __syncthreads();
        if (t == 0) ponder[0] = (red[0] + red[1] + red[2] + red[3]) * (-0.01f / 4096.f);
        return;
    }
    int count = *pcount;
    int wid = threadIdx.x >> 6, lane = threadIdx.x & 63;
    int r = blockIdx.x * 4 + wid;
    if (r >= count) return;
    int row = list[r];
    float cmb = 1.f - halt_accum[row];
    if (lane == 0) steps_out[row] = 16.f;
    const float* hr = h + (size_t)row * HID;
    float* th = tot_h + (size_t)row * HID;
#pragma unroll
    for (int q = 0; q < 4; q++) {
        int c = q * 256 + lane * 4;
        float4 hv = *(const float4*)(hr + c);
        float4 ov = *(const float4*)(th + c);
        ov.x += cmb * hv.x; ov.y += cmb * hv.y;
        ov.z += cmb * hv.z; ov.w += cmb * hv.w;
        *(float4*)(th + c) = ov;
    }
}

extern "C" void kernel_launch(void* const* d_in, const int* in_sizes, int n_in,
                              void* d_out, int out_size, void* d_ws, size_t ws_size,
                              hipStream_t stream) {
    const float* inputs = (const float*)d_in[0];
    const float* hidden = (const float*)d_in[1];
    const float* W_ih   = (const float*)d_in[2];
    const float* b_ih   = (const float*)d_in[3];
    const float* W_hh   = (const float*)d_in[4];
    const float* b_hh   = (const float*)d_in[5];
    const float* W_halt = (const float*)d_in[6];
    const float* b_halt = (const float*)d_in[7];
    float* out = (float*)d_out;

    float* ws = (float*)d_ws;
    const size_t NM = (size_t)BATCH * HID;               // 4M
    float* xbase = ws;                                   // 4M f32
    float* h     = xbase + NM;                           // 4M f32
    _Float16* B3ih = (_Float16*)(h + NM);                // 1024*3072 halfs
    _Float16* B3hh = B3ih + (size_t)HID * KV;
    _Float16* Ahi0 = B3hh + (size_t)HID * KV;            // 4M halfs each
    _Float16* Alo0 = Ahi0 + NM;
    _Float16* Ahi1 = Alo0 + NM;
    _Float16* Alo1 = Ahi1 + NM;
    float* flagcol = (float*)(Alo1 + NM);                // 1024
    float* halt_accum = flagcol + KDIM;                  // 4096
    float* tot_rem = halt_accum + BATCH;                 // 4096
    int* list0 = (int*)(tot_rem + BATCH);                // 4096
    int* list1 = list0 + BATCH;                          // 4096
    int* counts = list1 + BATCH;                         // 16

    _Float16* Ahi[2] = {Ahi0, Ahi1};
    _Float16* Alo[2] = {Alo0, Alo1};
    int* lists[2] = {list0, list1};

    float* tot_h = out;
    float* ponder = out + NM;
    float* steps_out = ponder + 1;

    // setup + split fused: inputs -> buf1 (dead after x_base), hidden -> buf0
    setup_kernel<<<16384, 256, 0, stream>>>(W_ih, W_hh, inputs, hidden,
                                            B3ih, B3hh, Ahi1, Alo1, Ahi0, Alo0,
                                            flagcol, list0, counts, halt_accum, tot_rem);

    // x_base = inputs @ W_ih[:, :-1].T + b_ih
    mfma_step_kernel<<<512, 256, 0, stream>>>(
        Ahi1, Alo1, B3ih, b_ih, nullptr, nullptr, 0.f, nullptr, nullptr,
        nullptr, nullptr, nullptr, xbase, 0);

    for (int t = 0; t < NSTEP; t++) {
        mfma_step_kernel<<<512, 256, 0, stream>>>(
            Ahi[t & 1], Alo[t & 1], B3hh, b_hh, xbase, flagcol,
            (t == 0) ? 1.f : 0.f, lists[t & 1], counts + t,
            h, Ahi[(t + 1) & 1], Alo[(t + 1) & 1], nullptr, 1);
        halt_kernel<<<1024, 256, 0, stream>>>(h, W_halt, b_halt,
                                              lists[t & 1], counts + t,
                                              lists[(t + 1) & 1], counts + t + 1,
                                              halt_accum, tot_rem, tot_h, steps_out,
                                              t + 1, (t == 0) ? 1 : 0);
    }
    epilogue_kernel<<<1025, 256, 0, stream>>>(h, lists[1], counts + 15,
                                              halt_accum, tot_rem, tot_h, steps_out, ponder);
}

// Round 6
// 878.959 us; speedup vs baseline: 1.1158x; 1.0352x over previous
//
#include <hip/hip_runtime.h>
#include <math.h>
#include <stdint.h>

#define BATCH 4096
#define HID   1024
#define KDIM  1024
#define NSTEP 15
#define KV    3072      // virtual K: [A_hi·B_hi | A_hi·B_lo | A_lo·B_hi]
#define NCHUNK (KV / 64)

// MFMA GEMM, R0 geometry + global_load_lds staging (m97 ladder step):
// 256 thr = 4 waves; block tile 128(M) x 64(N); BK=64 virtual-k.
// Wave w: rows (w&1)*64, cols (w>>1)*32; frags 4(M) x 2(N) of 16x16x32 f16.
// Staging: __builtin_amdgcn_global_load_lds width-16 — no ds_write, no staging
// VGPRs. LDS layout LINEAR [row][64] (rule #21): DMA dest = base + lane*16B;
// bank conflicts handled by XOR swizzle: within a row, 16B-granule g holds
// source granule g ^ (row&7); ds_read uses the same XOR -> <=2-way (free).
// R5 lesson: LDS-free gather path abandoned (TA-serialized, 108us tails).

typedef _Float16 half8 __attribute__((ext_vector_type(8)));
typedef float floatx4 __attribute__((ext_vector_type(4)));

typedef __attribute__((address_space(3))) uint32_t lds_u32_t;
typedef __attribute__((address_space(1))) const uint32_t gl_u32_t;

__device__ __forceinline__ _Float16 f16hi(float x) { return (_Float16)x; }

__device__ __forceinline__ void gl_lds16(const _Float16* g, _Float16* l) {
    __builtin_amdgcn_global_load_lds((gl_u32_t*)g, (lds_u32_t*)l, 16, 0, 0);
}

// B3[n][kv]: kv<1024: hi(W[n][kv]); 1024..2047: lo; 2048..3071: hi (dup).
// Also: split inputs/hidden into f16 hi/lo, init lists/accums.
__global__ __launch_bounds__(256) void setup_kernel(
    const float* __restrict__ W_ih, const float* __restrict__ W_hh,
    const float* __restrict__ inputs, const float* __restrict__ hidden,
    _Float16* __restrict__ B3ih, _Float16* __restrict__ B3hh,
    _Float16* __restrict__ Ihi, _Float16* __restrict__ Ilo,
    _Float16* __restrict__ Hhi, _Float16* __restrict__ Hlo,
    float* __restrict__ flagcol, int* __restrict__ list0, int* __restrict__ counts,
    float* __restrict__ halt_accum, float* __restrict__ tot_rem) {
    size_t idx = (size_t)blockIdx.x * 256 + threadIdx.x;   // grid 16384 -> 4M
    {   // split inputs -> I, hidden -> H
        float x = inputs[idx];
        _Float16 h = f16hi(x);
        Ihi[idx] = h; Ilo[idx] = (_Float16)(x - (float)h);
        float y = hidden[idx];
        _Float16 g = f16hi(y);
        Hhi[idx] = g; Hlo[idx] = (_Float16)(y - (float)g);
    }
    if (idx < (size_t)KDIM * KDIM) {
        int n = (int)(idx >> 10), k = (int)(idx & 1023);
        float w = W_hh[idx];
        _Float16 hi = f16hi(w);
        _Float16 lo = (_Float16)(w - (float)hi);
        size_t base = (size_t)n * KV;
        B3hh[base + k] = hi; B3hh[base + 1024 + k] = lo; B3hh[base + 2048 + k] = hi;
        float w2 = W_ih[(size_t)n * 1025 + k];
        _Float16 hi2 = f16hi(w2);
        _Float16 lo2 = (_Float16)(w2 - (float)hi2);
        B3ih[base + k] = hi2; B3ih[base + 1024 + k] = lo2; B3ih[base + 2048 + k] = hi2;
    }
    if (idx < BATCH) { list0[idx] = idx; halt_accum[idx] = 0.f; tot_rem[idx] = 0.f; }
    if (idx < KDIM) flagcol[idx] = W_ih[idx * 1025 + 1024];
    if (idx < 16) counts[idx] = (idx == 0) ? BATCH : 0;
}

// mode 0: xout[row] = A @ B^T + bias (fp32)
// mode 1: h = tanh(acc + xbase + flag*flagcol + bias); store h fp32 + hi/lo f16
__global__ __launch_bounds__(256) void mfma_step_kernel(
    const _Float16* __restrict__ Ahi, const _Float16* __restrict__ Alo,
    const _Float16* __restrict__ B3, const float* __restrict__ bias,
    const float* __restrict__ xbase, const float* __restrict__ flagcol, float flag,
    const int* __restrict__ list, const int* __restrict__ pcount,
    float* __restrict__ hout, _Float16* __restrict__ houthi, _Float16* __restrict__ houtlo,
    float* __restrict__ xout, int mode) {
    int count = pcount ? *pcount : BATCH;
    int row0 = blockIdx.x * 128;
    if (row0 >= count) return;
    int col0 = blockIdx.y * 64;

    // linear LDS: A 2x[128][64], B 2x[64][64] halfs = 48 KiB total
    __shared__ _Float16 AsmL[2 * 128 * 64];
    __shared__ _Float16 BsmL[2 * 64 * 64];

    int t = threadIdx.x;
    int lane = t & 63, w = t >> 6;
    int wm = (w & 1) * 64, wn = (w >> 1) * 32;
    int l15 = lane & 15, l4 = lane >> 4;

    // staging source offsets: lane covers LDS row r = s*8 + (lane>>3),
    // granule qk = lane&7; source granule = qk ^ (r&7) = (lane&7)^(lane>>3)
    // (inverse swizzle on SOURCE so LINEAR DMA dest + swizzled read match).
    int swg = ((lane & 7) ^ (lane >> 3)) << 3;      // swizzled granule offset (halfs)
    size_t aoff[4];                                  // A: wave w stages rows w*32..w*32+31
#pragma unroll
    for (int j = 0; j < 4; j++) {
        int r = w * 32 + j * 8 + (lane >> 3);
        int grow = row0 + r;
        int g = (grow < count) ? (list ? list[grow] : grow) : 0;
        aoff[j] = (size_t)g * KDIM + swg;
    }
    size_t boff[2];                                  // B: wave w stages rows w*16..w*16+15
#pragma unroll
    for (int j = 0; j < 2; j++) {
        int r = w * 16 + j * 8 + (lane >> 3);
        boff[j] = (size_t)(col0 + r) * KV + swg;
    }

    floatx4 acc[4][2];
#pragma unroll
    for (int i = 0; i < 4; i++)
#pragma unroll
        for (int j = 0; j < 2; j++) acc[i][j] = (floatx4)(0.f);

#define STAGE(buf, c) do {                                                    \
        int k0v_ = (c) << 6;                                                  \
        const _Float16* As_ = (k0v_ < 2048) ? Ahi : Alo; /* segs [hi,hi,lo] */ \
        int kp_ = k0v_ & 1023;                                                \
        _Pragma("unroll")                                                     \
        for (int j = 0; j < 4; j++)                                           \
            gl_lds16(As_ + aoff[j] + kp_,                                     \
                     &AsmL[(buf) * 8192 + (w * 4 + j) * 512]);                \
        _Pragma("unroll")                                                     \
        for (int j = 0; j < 2; j++)                                           \
            gl_lds16(B3 + boff[j] + k0v_,                                     \
                     &BsmL[(buf) * 4096 + (w * 2 + j) * 512]);                \
    } while (0)

    // ds_read slot for granule (ks*4+l4) of row: slot = (ks*4+l4) ^ (row&7);
    // row&7 == l15&7 for all fragment rows (wm, wn, fi*16 are multiples of 8).
#define MFMA_CHUNK(buf) do {                                                  \
        _Pragma("unroll")                                                     \
        for (int ks = 0; ks < 2; ks++) {                                      \
            int slot = (((ks * 4 + l4) ^ (l15 & 7)) << 3);                    \
            half8 af[4], bf[2];                                               \
            _Pragma("unroll")                                                 \
            for (int fi = 0; fi < 4; fi++)                                    \
                af[fi] = *(const half8*)(&AsmL[(buf) * 8192 +                 \
                              (wm + fi * 16 + l15) * 64 + slot]);             \
            _Pragma("unroll")                                                 \
            for (int fj = 0; fj < 2; fj++)                                    \
                bf[fj] = *(const half8*)(&BsmL[(buf) * 4096 +                 \
                              (wn + fj * 16 + l15) * 64 + slot]);             \
            _Pragma("unroll")                                                 \
            for (int fi = 0; fi < 4; fi++)                                    \
                _Pragma("unroll")                                             \
                for (int fj = 0; fj < 2; fj++)                                \
                    acc[fi][fj] = __builtin_amdgcn_mfma_f32_16x16x32_f16(     \
                        af[fi], bf[fj], acc[fi][fj], 0, 0, 0);                \
        }                                                                     \
    } while (0)

    STAGE(0, 0);
    __syncthreads();

    int p = 0;
    for (int it = 0; it < NCHUNK; it++) {
        if (it + 1 < NCHUNK) STAGE(p ^ 1, it + 1);   // DMA flies under MFMA
        MFMA_CHUNK(p);
        __syncthreads();                              // drains vmcnt: buf p^1 ready
        p ^= 1;
    }

#undef STAGE
#undef MFMA_CHUNK

    // epilogue: C/D layout col = lane&15, row = (lane>>4)*4 + reg  [m89-verified]
#pragma unroll
    for (int fi = 0; fi < 4; fi++) {
#pragma unroll
        for (int rr = 0; rr < 4; rr++) {
            int lm = wm + fi * 16 + l4 * 4 + rr;
            int grd = row0 + lm;
            if (grd >= count) continue;
            int g = list ? list[grd] : grd;
#pragma unroll
            for (int fj = 0; fj < 2; fj++) {
                int c = col0 + wn + fj * 16 + l15;
                float v = acc[fi][fj][rr];
                if (mode == 0) {
                    xout[(size_t)g * KDIM + c] = v + bias[c];
                } else {
                    v += xbase[(size_t)g * KDIM + c] + flag * flagcol[c] + bias[c];
                    v = tanhf(v);
                    hout[(size_t)g * KDIM + c] = v;
                    _Float16 hi = f16hi(v);
                    houthi[(size_t)g * KDIM + c] = hi;
                    houtlo[(size_t)g * KDIM + c] = (_Float16)(v - (float)hi);
                }
            }
        }
    }
}

// One wave per active row: halt logit, sigmoid, halting state machine,
// tot_h accumulation into d_out, compaction of next-step list.  (R1-verified)
__global__ __launch_bounds__(256) void halt_kernel(
    const float* __restrict__ h, const float* __restrict__ W_halt,
    const float* __restrict__ b_halt,
    const int* __restrict__ list, const int* __restrict__ pcount,
    int* __restrict__ list_next, int* __restrict__ pcount_next,
    float* __restrict__ halt_accum, float* __restrict__ tot_rem,
    float* __restrict__ tot_h, float* __restrict__ steps_out,
    int stepnum, int first) {
    int count = *pcount;
    int wid = threadIdx.x >> 6, lane = threadIdx.x & 63;
    int r = blockIdx.x * 4 + wid;
    if (r >= count) return;
    int row = list[r];
    const float* hr = h + (size_t)row * HID;

    float dot = 0.f;
#pragma unroll
    for (int q = 0; q < 4; q++) {
        int c = q * 256 + lane * 4;
        float4 hv = *(const float4*)(hr + c);
        float4 wv = *(const float4*)(W_halt + c);
        dot += hv.x * wv.x + hv.y * wv.y + hv.z * wv.z + hv.w * wv.w;
    }
#pragma unroll
    for (int off = 32; off > 0; off >>= 1) dot += __shfl_down(dot, off);

    float combined = 0.f;
    if (lane == 0) {
        float p = 1.f / (1.f + expf(-(dot + b_halt[0])));
        float S = halt_accum[row] + p;
        halt_accum[row] = S;
        tot_rem[row] += p;
        bool ending = (S + p) > 0.99f;      // budget = 1 - PONDER_EPS
        if (ending) {
            combined = p + (1.f - S);
            steps_out[row] = (float)stepnum;
        } else {
            combined = p;
            int idx = atomicAdd(pcount_next, 1);
            list_next[idx] = row;
        }
    }
    combined = __shfl(combined, 0);

    float* th = tot_h + (size_t)row * HID;
#pragma unroll
    for (int q = 0; q < 4; q++) {
        int c = q * 256 + lane * 4;
        float4 hv = *(const float4*)(hr + c);
        float4 ov;
        if (first) {
            ov.x = combined * hv.x; ov.y = combined * hv.y;
            ov.z = combined * hv.z; ov.w = combined * hv.w;
        } else {
            ov = *(const float4*)(th + c);
            ov.x += combined * hv.x; ov.y += combined * hv.y;
            ov.z += combined * hv.z; ov.w += combined * hv.w;
        }
        *(float4*)(th + c) = ov;
    }
}

// blocks 0..1023: survivors get (1 - halt_accum) * h_final, steps = 16.
// block 1024: ponder reduction.
__global__ __launch_bounds__(256) void epilogue_kernel(
    const float* __restrict__ h, const int* __restrict__ list,
    const int* __restrict__ pcount, const float* __restrict__ halt_accum,
    const float* __restrict__ tot_rem,
    float* __restrict__ tot_h, float* __restrict__ steps_out,
    float* __restrict__ ponder) {
    if (blockIdx.x == 1024) {
        __shared__ float red[4];
        int t = threadIdx.x;
        float v = 0.f;
#pragma unroll
        for (int i = 0; i < 16; i++) v += tot_rem[t + i * 256];
#pragma unroll
        for (int off = 32; off > 0; off >>= 1) v += __shfl_down(v, off);
        int lane = t & 63, wid = t >> 6;
        if (lane == 0) red[wid] = v;
        __syncthreads();
        if (t == 0) ponder[0] = (red[0] + red[1] + red[2] + red[3]) * (-0.01f / 4096.f);
        return;
    }
    int count = *pcount;
    int wid = threadIdx.x >> 6, lane = threadIdx.x & 63;
    int r = blockIdx.x * 4 + wid;
    if (r >= count) return;
    int row = list[r];
    float cmb = 1.f - halt_accum[row];
    if (lane == 0) steps_out[row] = 16.f;
    const float* hr = h + (size_t)row * HID;
    float* th = tot_h + (size_t)row * HID;
#pragma unroll
    for (int q = 0; q < 4; q++) {
        int c = q * 256 + lane * 4;
        float4 hv = *(const float4*)(hr + c);
        float4 ov = *(const float4*)(th + c);
        ov.x += cmb * hv.x; ov.y += cmb * hv.y;
        ov.z += cmb * hv.z; ov.w += cmb * hv.w;
        *(float4*)(th + c) = ov;
    }
}

extern "C" void kernel_launch(void* const* d_in, const int* in_sizes, int n_in,
                              void* d_out, int out_size, void* d_ws, size_t ws_size,
                              hipStream_t stream) {
    const float* inputs = (const float*)d_in[0];
    const float* hidden = (const float*)d_in[1];
    const float* W_ih   = (const float*)d_in[2];
    const float* b_ih   = (const float*)d_in[3];
    const float* W_hh   = (const float*)d_in[4];
    const float* b_hh   = (const float*)d_in[5];
    const float* W_halt = (const float*)d_in[6];
    const float* b_halt = (const float*)d_in[7];
    float* out = (float*)d_out;

    float* ws = (float*)d_ws;
    const size_t NM = (size_t)BATCH * HID;               // 4M
    float* xbase = ws;                                   // 4M f32
    float* h     = xbase + NM;                           // 4M f32
    _Float16* B3ih = (_Float16*)(h + NM);                // 1024*3072 halfs
    _Float16* B3hh = B3ih + (size_t)HID * KV;
    _Float16* Ahi0 = B3hh + (size_t)HID * KV;            // 4M halfs each
    _Float16* Alo0 = Ahi0 + NM;
    _Float16* Ahi1 = Alo0 + NM;
    _Float16* Alo1 = Ahi1 + NM;
    float* flagcol = (float*)(Alo1 + NM);                // 1024
    float* halt_accum = flagcol + KDIM;                  // 4096
    float* tot_rem = halt_accum + BATCH;                 // 4096
    int* list0 = (int*)(tot_rem + BATCH);                // 4096
    int* list1 = list0 + BATCH;                          // 4096
    int* counts = list1 + BATCH;                         // 16

    _Float16* Ahi[2] = {Ahi0, Ahi1};
    _Float16* Alo[2] = {Alo0, Alo1};
    int* lists[2] = {list0, list1};

    float* tot_h = out;
    float* ponder = out + NM;
    float* steps_out = ponder + 1;

    // setup + split fused: inputs -> buf1 (dead after x_base), hidden -> buf0
    setup_kernel<<<16384, 256, 0, stream>>>(W_ih, W_hh, inputs, hidden,
                                            B3ih, B3hh, Ahi1, Alo1, Ahi0, Alo0,
                                            flagcol, list0, counts, halt_accum, tot_rem);

    // x_base = inputs @ W_ih[:, :-1].T + b_ih
    mfma_step_kernel<<<dim3(32, 16), 256, 0, stream>>>(
        Ahi1, Alo1, B3ih, b_ih, nullptr, nullptr, 0.f, nullptr, nullptr,
        nullptr, nullptr, nullptr, xbase, 0);

    for (int t = 0; t < NSTEP; t++) {
        mfma_step_kernel<<<dim3(32, 16), 256, 0, stream>>>(
            Ahi[t & 1], Alo[t & 1], B3hh, b_hh, xbase, flagcol,
            (t == 0) ? 1.f : 0.f, lists[t & 1], counts + t,
            h, Ahi[(t + 1) & 1], Alo[(t + 1) & 1], nullptr, 1);
        halt_kernel<<<1024, 256, 0, stream>>>(h, W_halt, b_halt,
                                              lists[t & 1], counts + t,
                                              lists[(t + 1) & 1], counts + t + 1,
                                              halt_accum, tot_rem, tot_h, steps_out,
                                              t + 1, (t == 0) ? 1 : 0);
    }
    epilogue_kernel<<<1025, 256, 0, stream>>>(h, lists[1], counts + 15,
                                              halt_accum, tot_rem, tot_h, steps_out, ponder);
}

// Round 7
// 838.135 us; speedup vs baseline: 1.1701x; 1.0487x over previous
//
#include <hip/hip_runtime.h>
#include <math.h>
#include <stdint.h>

#define BATCH 4096
#define HID   1024
#define KDIM  1024
#define NSTEP 15
#define KV    3072      // virtual K: [A_hi·B_hi | A_hi·B_lo | A_lo·B_hi]
#define NCHUNK (KV / 64)

// BARRIER-FREE MFMA GEMM: 64 threads = 1 wave per block, wave tile 64x64
// (4x4 frags of 16x16x32 f16 -> 0.5 LDS-reads/MFMA, half of R0's 64x32).
// Each wave stages its OWN double-buffered LDS (A,B 2x8KB); same-wave
// ds_write -> ds_read ordering needs only lgkmcnt (compiler-counted): NO
// __syncthreads, no collective vmcnt drain, waves free-run (R0-R2 showed
// barrier-lockstep + shared LDS unit = 3.2K cyc/chunk wall).
// Staging loads stay R0-style coalesced row loads (R3/R5 lesson: per-lane
// gathered MFMA-fragment loads TA-serialize). XOR granule swizzle (R6-
// verified: conflicts=0, absmax unchanged): store granule q at slot
// q^(row&7); read slot (ks*4+l4)^(l15&7).

typedef _Float16 half8 __attribute__((ext_vector_type(8)));
typedef float floatx4 __attribute__((ext_vector_type(4)));

__device__ __forceinline__ _Float16 f16hi(float x) { return (_Float16)x; }

// B3[n][kv]: kv<1024: hi(W[n][kv]); 1024..2047: lo; 2048..3071: hi (dup).
// Also: split inputs/hidden into f16 hi/lo, init lists/accums.
__global__ __launch_bounds__(256) void setup_kernel(
    const float* __restrict__ W_ih, const float* __restrict__ W_hh,
    const float* __restrict__ inputs, const float* __restrict__ hidden,
    _Float16* __restrict__ B3ih, _Float16* __restrict__ B3hh,
    _Float16* __restrict__ Ihi, _Float16* __restrict__ Ilo,
    _Float16* __restrict__ Hhi, _Float16* __restrict__ Hlo,
    float* __restrict__ flagcol, int* __restrict__ list0, int* __restrict__ counts,
    float* __restrict__ halt_accum, float* __restrict__ tot_rem) {
    size_t idx = (size_t)blockIdx.x * 256 + threadIdx.x;   // grid 16384 -> 4M
    {   // split inputs -> I, hidden -> H
        float x = inputs[idx];
        _Float16 h = f16hi(x);
        Ihi[idx] = h; Ilo[idx] = (_Float16)(x - (float)h);
        float y = hidden[idx];
        _Float16 g = f16hi(y);
        Hhi[idx] = g; Hlo[idx] = (_Float16)(y - (float)g);
    }
    if (idx < (size_t)KDIM * KDIM) {
        int n = (int)(idx >> 10), k = (int)(idx & 1023);
        float w = W_hh[idx];
        _Float16 hi = f16hi(w);
        _Float16 lo = (_Float16)(w - (float)hi);
        size_t base = (size_t)n * KV;
        B3hh[base + k] = hi; B3hh[base + 1024 + k] = lo; B3hh[base + 2048 + k] = hi;
        float w2 = W_ih[(size_t)n * 1025 + k];
        _Float16 hi2 = f16hi(w2);
        _Float16 lo2 = (_Float16)(w2 - (float)hi2);
        B3ih[base + k] = hi2; B3ih[base + 1024 + k] = lo2; B3ih[base + 2048 + k] = hi2;
    }
    if (idx < BATCH) { list0[idx] = idx; halt_accum[idx] = 0.f; tot_rem[idx] = 0.f; }
    if (idx < KDIM) flagcol[idx] = W_ih[idx * 1025 + 1024];
    if (idx < 16) counts[idx] = (idx == 0) ? BATCH : 0;
}

// mode 0: xout[row] = A @ B^T + bias (fp32)
// mode 1: h = tanh(acc + xbase + flag*flagcol + bias); store h fp32 + hi/lo f16
// Grid dim3(64,16), 64 threads: blockIdx.x over M (64-row tiles), .y over N.
__global__ __launch_bounds__(64, 1) void mfma_step_kernel(
    const _Float16* __restrict__ Ahi, const _Float16* __restrict__ Alo,
    const _Float16* __restrict__ B3, const float* __restrict__ bias,
    const float* __restrict__ xbase, const float* __restrict__ flagcol, float flag,
    const int* __restrict__ list, const int* __restrict__ pcount,
    float* __restrict__ hout, _Float16* __restrict__ houthi, _Float16* __restrict__ houtlo,
    float* __restrict__ xout, int mode) {
    int count = pcount ? *pcount : BATCH;
    int row0 = blockIdx.x * 64;
    if (row0 >= count) return;
    int col0 = blockIdx.y * 64;

    // per-wave double-buffered tiles: 2 x 64x64 halfs each = 32 KiB total
    __shared__ _Float16 Asm[2][64 * 64];
    __shared__ _Float16 Bsm[2][64 * 64];

    int lane = threadIdx.x;
    int l15 = lane & 15, l4 = lane >> 4;
    int lr = lane >> 3, lq = lane & 7;          // staging: row-sub, granule

    // staging source offsets (u32 half-index): load j covers rows j*8+lr,
    // granule lq (linear source); A rows gathered via list.
    uint32_t aoffu[8], boffu[8];
#pragma unroll
    for (int j = 0; j < 8; j++) {
        int r = j * 8 + lr;
        int grow = row0 + r;
        int g = (grow < count) ? (list ? list[grow] : grow) : 0;
        aoffu[j] = (uint32_t)g * KDIM + lq * 8;
        boffu[j] = (uint32_t)(col0 + r) * KV + lq * 8;
    }
    // LDS dst (halfs): slot = lq ^ (r&7) = lq ^ lr (j-independent), + j*512
    int dst0 = lr * 64 + ((lq ^ lr) << 3);

    floatx4 acc[4][4];
#pragma unroll
    for (int i = 0; i < 4; i++)
#pragma unroll
        for (int j = 0; j < 4; j++) acc[i][j] = (floatx4)(0.f);

    half8 avE[8], bvE[8], avO[8], bvO[8];       // two named stage sets

#define LOADS(av, bv, c) do {                                                 \
        int k0v_ = (c) << 6;                                                  \
        const _Float16* As_ = (k0v_ < 2048) ? Ahi : Alo; /* segs [hi,hi,lo] */ \
        int kp_ = k0v_ & 1023;                                                \
        _Pragma("unroll")                                                     \
        for (int j = 0; j < 8; j++) {                                         \
            av[j] = *(const half8*)(Ahi + 0 + aoffu[j] + kp_ + (As_ - Ahi));  \
            bv[j] = *(const half8*)(B3 + boffu[j] + k0v_);                    \
        }                                                                     \
    } while (0)

#define WRITES(buf, av, bv) do {                                              \
        _Pragma("unroll")                                                     \
        for (int j = 0; j < 8; j++) {                                         \
            *(half8*)(&Asm[buf][dst0 + j * 512]) = av[j];                     \
            *(half8*)(&Bsm[buf][dst0 + j * 512]) = bv[j];                     \
        }                                                                     \
    } while (0)

#define MFMA_CHUNK(buf) do {                                                  \
        _Pragma("unroll")                                                     \
        for (int ks = 0; ks < 2; ks++) {                                      \
            int slot = (((ks * 4 + l4) ^ (l15 & 7)) << 3);                    \
            half8 af[4], bf[4];                                               \
            _Pragma("unroll")                                                 \
            for (int f = 0; f < 4; f++) {                                     \
                af[f] = *(const half8*)(&Asm[buf][(f * 16 + l15) * 64 + slot]); \
                bf[f] = *(const half8*)(&Bsm[buf][(f * 16 + l15) * 64 + slot]); \
            }                                                                 \
            _Pragma("unroll")                                                 \
            for (int fi = 0; fi < 4; fi++)                                    \
                _Pragma("unroll")                                             \
                for (int fj = 0; fj < 4; fj++)                                \
                    acc[fi][fj] = __builtin_amdgcn_mfma_f32_16x16x32_f16(     \
                        af[fi], bf[fj], acc[fi][fj], 0, 0, 0);                \
        }                                                                     \
    } while (0)

    // prologue: buf0 <- c0; setO holds c1 (in flight)
    LOADS(avE, bvE, 0);
    WRITES(0, avE, bvE);        // waits vmcnt for setE only
    LOADS(avO, bvO, 1);

    // steady state (buf0 = even chunks, buf1 = odd; no barriers anywhere):
    for (int it = 0; it < NCHUNK; it += 2) {
        WRITES(1, avO, bvO);                    // chunk it+1 -> buf1
        if (it + 2 < NCHUNK) LOADS(avE, bvE, it + 2);
        MFMA_CHUNK(0);                          // chunk it
        if (it + 2 < NCHUNK) WRITES(0, avE, bvE);   // chunk it+2 -> buf0
        if (it + 3 < NCHUNK) LOADS(avO, bvO, it + 3);
        MFMA_CHUNK(1);                          // chunk it+1
    }

#undef LOADS
#undef WRITES
#undef MFMA_CHUNK

    // epilogue: C/D layout col = lane&15, row = (lane>>4)*4 + reg  [m89-verified]
#pragma unroll
    for (int fi = 0; fi < 4; fi++) {
#pragma unroll
        for (int rr = 0; rr < 4; rr++) {
            int lm = fi * 16 + l4 * 4 + rr;
            int grd = row0 + lm;
            if (grd >= count) continue;
            int g = list ? list[grd] : grd;
#pragma unroll
            for (int fj = 0; fj < 4; fj++) {
                int c = col0 + fj * 16 + l15;
                float v = acc[fi][fj][rr];
                if (mode == 0) {
                    xout[(size_t)g * KDIM + c] = v + bias[c];
                } else {
                    v += xbase[(size_t)g * KDIM + c] + flag * flagcol[c] + bias[c];
                    v = tanhf(v);
                    hout[(size_t)g * KDIM + c] = v;
                    _Float16 hi = f16hi(v);
                    houthi[(size_t)g * KDIM + c] = hi;
                    houtlo[(size_t)g * KDIM + c] = (_Float16)(v - (float)hi);
                }
            }
        }
    }
}

// One wave per active row: halt logit, sigmoid, halting state machine,
// tot_h accumulation into d_out, compaction of next-step list.  (R1-verified)
__global__ __launch_bounds__(256) void halt_kernel(
    const float* __restrict__ h, const float* __restrict__ W_halt,
    const float* __restrict__ b_halt,
    const int* __restrict__ list, const int* __restrict__ pcount,
    int* __restrict__ list_next, int* __restrict__ pcount_next,
    float* __restrict__ halt_accum, float* __restrict__ tot_rem,
    float* __restrict__ tot_h, float* __restrict__ steps_out,
    int stepnum, int first) {
    int count = *pcount;
    int wid = threadIdx.x >> 6, lane = threadIdx.x & 63;
    int r = blockIdx.x * 4 + wid;
    if (r >= count) return;
    int row = list[r];
    const float* hr = h + (size_t)row * HID;

    float dot = 0.f;
#pragma unroll
    for (int q = 0; q < 4; q++) {
        int c = q * 256 + lane * 4;
        float4 hv = *(const float4*)(hr + c);
        float4 wv = *(const float4*)(W_halt + c);
        dot += hv.x * wv.x + hv.y * wv.y + hv.z * wv.z + hv.w * wv.w;
    }
#pragma unroll
    for (int off = 32; off > 0; off >>= 1) dot += __shfl_down(dot, off);

    float combined = 0.f;
    if (lane == 0) {
        float p = 1.f / (1.f + expf(-(dot + b_halt[0])));
        float S = halt_accum[row] + p;
        halt_accum[row] = S;
        tot_rem[row] += p;
        bool ending = (S + p) > 0.99f;      // budget = 1 - PONDER_EPS
        if (ending) {
            combined = p + (1.f - S);
            steps_out[row] = (float)stepnum;
        } else {
            combined = p;
            int idx = atomicAdd(pcount_next, 1);
            list_next[idx] = row;
        }
    }
    combined = __shfl(combined, 0);

    float* th = tot_h + (size_t)row * HID;
#pragma unroll
    for (int q = 0; q < 4; q++) {
        int c = q * 256 + lane * 4;
        float4 hv = *(const float4*)(hr + c);
        float4 ov;
        if (first) {
            ov.x = combined * hv.x; ov.y = combined * hv.y;
            ov.z = combined * hv.z; ov.w = combined * hv.w;
        } else {
            ov = *(const float4*)(th + c);
            ov.x += combined * hv.x; ov.y += combined * hv.y;
            ov.z += combined * hv.z; ov.w += combined * hv.w;
        }
        *(float4*)(th + c) = ov;
    }
}

// blocks 0..1023: survivors get (1 - halt_accum) * h_final, steps = 16.
// block 1024: ponder reduction.
__global__ __launch_bounds__(256) void epilogue_kernel(
    const float* __restrict__ h, const int* __restrict__ list,
    const int* __restrict__ pcount, const float* __restrict__ halt_accum,
    const float* __restrict__ tot_rem,
    float* __restrict__ tot_h, float* __restrict__ steps_out,
    float* __restrict__ ponder) {
    if (blockIdx.x == 1024) {
        __shared__ float red[4];
        int t = threadIdx.x;
        float v = 0.f;
#pragma unroll
        for (int i = 0; i < 16; i++) v += tot_rem[t + i * 256];
#pragma unroll
        for (int off = 32; off > 0; off >>= 1) v += __shfl_down(v, off);
        int lane = t & 63, wid = t >> 6;
        if (lane == 0) red[wid] = v;
        __syncthreads();
        if (t == 0) ponder[0] = (red[0] + red[1] + red[2] + red[3]) * (-0.01f / 4096.f);
        return;
    }
    int count = *pcount;
    int wid = threadIdx.x >> 6, lane = threadIdx.x & 63;
    int r = blockIdx.x * 4 + wid;
    if (r >= count) return;
    int row = list[r];
    float cmb = 1.f - halt_accum[row];
    if (lane == 0) steps_out[row] = 16.f;
    const float* hr = h + (size_t)row * HID;
    float* th = tot_h + (size_t)row * HID;
#pragma unroll
    for (int q = 0; q < 4; q++) {
        int c = q * 256 + lane * 4;
        float4 hv = *(const float4*)(hr + c);
        float4 ov = *(const float4*)(th + c);
        ov.x += cmb * hv.x; ov.y += cmb * hv.y;
        ov.z += cmb * hv.z; ov.w += cmb * hv.w;
        *(float4*)(th + c) = ov;
    }
}

extern "C" void kernel_launch(void* const* d_in, const int* in_sizes, int n_in,
                              void* d_out, int out_size, void* d_ws, size_t ws_size,
                              hipStream_t stream) {
    const float* inputs = (const float*)d_in[0];
    const float* hidden = (const float*)d_in[1];
    const float* W_ih   = (const float*)d_in[2];
    const float* b_ih   = (const float*)d_in[3];
    const float* W_hh   = (const float*)d_in[4];
    const float* b_hh   = (const float*)d_in[5];
    const float* W_halt = (const float*)d_in[6];
    const float* b_halt = (const float*)d_in[7];
    float* out = (float*)d_out;

    float* ws = (float*)d_ws;
    const size_t NM = (size_t)BATCH * HID;               // 4M
    float* xbase = ws;                                   // 4M f32
    float* h     = xbase + NM;                           // 4M f32
    _Float16* B3ih = (_Float16*)(h + NM);                // 1024*3072 halfs
    _Float16* B3hh = B3ih + (size_t)HID * KV;
    _Float16* Ahi0 = B3hh + (size_t)HID * KV;            // 4M halfs each
    _Float16* Alo0 = Ahi0 + NM;
    _Float16* Ahi1 = Alo0 + NM;
    _Float16* Alo1 = Ahi1 + NM;
    float* flagcol = (float*)(Alo1 + NM);                // 1024
    float* halt_accum = flagcol + KDIM;                  // 4096
    float* tot_rem = halt_accum + BATCH;                 // 4096
    int* list0 = (int*)(tot_rem + BATCH);                // 4096
    int* list1 = list0 + BATCH;                          // 4096
    int* counts = list1 + BATCH;                         // 16

    _Float16* Ahi[2] = {Ahi0, Ahi1};
    _Float16* Alo[2] = {Alo0, Alo1};
    int* lists[2] = {list0, list1};

    float* tot_h = out;
    float* ponder = out + NM;
    float* steps_out = ponder + 1;

    // setup + split fused: inputs -> buf1 (dead after x_base), hidden -> buf0
    setup_kernel<<<16384, 256, 0, stream>>>(W_ih, W_hh, inputs, hidden,
                                            B3ih, B3hh, Ahi1, Alo1, Ahi0, Alo0,
                                            flagcol, list0, counts, halt_accum, tot_rem);

    // x_base = inputs @ W_ih[:, :-1].T + b_ih
    mfma_step_kernel<<<dim3(64, 16), 64, 0, stream>>>(
        Ahi1, Alo1, B3ih, b_ih, nullptr, nullptr, 0.f, nullptr, nullptr,
        nullptr, nullptr, nullptr, xbase, 0);

    for (int t = 0; t < NSTEP; t++) {
        mfma_step_kernel<<<dim3(64, 16), 64, 0, stream>>>(
            Ahi[t & 1], Alo[t & 1], B3hh, b_hh, xbase, flagcol,
            (t == 0) ? 1.f : 0.f, lists[t & 1], counts + t,
            h, Ahi[(t + 1) & 1], Alo[(t + 1) & 1], nullptr, 1);
        halt_kernel<<<1024, 256, 0, stream>>>(h, W_halt, b_halt,
                                              lists[t & 1], counts + t,
                                              lists[(t + 1) & 1], counts + t + 1,
                                              halt_accum, tot_rem, tot_h, steps_out,
                                              t + 1, (t == 0) ? 1 : 0);
    }
    epilogue_kernel<<<1025, 256, 0, stream>>>(h, lists[1], counts + 15,
                                              halt_accum, tot_rem, tot_h, steps_out, ponder);
}

// Round 8
// 756.429 us; speedup vs baseline: 1.2965x; 1.1080x over previous
//
#include <hip/hip_runtime.h>
#include <math.h>
#include <stdint.h>

#define BATCH 4096
#define HID   1024
#define KDIM  1024
#define NSTEP 15
#define KV    3072      // virtual K: [A_hi·B_hi | A_hi·B_lo | A_lo·B_hi]
#define NCHUNK (KV / 64)
#define TAILTHRESH 2048
#define SKT 4           // split-K factor for tail steps
#define CPB (NCHUNK / SKT)   // chunks per tail block = 12

// MFMA GEMM = R0-verified 128x64 cooperative path (63.4us @ full count),
// UNCHANGED for count >= TAILTHRESH (only blockIdx.z==0 runs).
// For count < TAILTHRESH: split-K=4 — all 4 z-blocks run 12 chunks each
// (serial K depth 48 -> 12; R0-R7 showed tail cost ~ serial chunk chain),
// writing fp32 partials indexed by LIST POSITION (buffers 2048x1024 each).
// halt_kernel fuses the combine for tails: h = tanh(xbase+b_hh+sum(p)),
// in-register dot with W_halt, writes hi/lo f16 for the next step's A.
#define TMM 128
#define TNN 64
#define LDAH 72         // LDS row stride in halfs (144B)

typedef _Float16 half8 __attribute__((ext_vector_type(8)));
typedef _Float16 half4v __attribute__((ext_vector_type(4)));
typedef float floatx4 __attribute__((ext_vector_type(4)));

__device__ __forceinline__ _Float16 f16hi(float x) { return (_Float16)x; }

// B3[n][kv]: kv<1024: hi(W[n][kv]); 1024..2047: lo; 2048..3071: hi (dup).
// Also: split inputs/hidden into f16 hi/lo, init lists/accums.
__global__ __launch_bounds__(256) void setup_kernel(
    const float* __restrict__ W_ih, const float* __restrict__ W_hh,
    const float* __restrict__ inputs, const float* __restrict__ hidden,
    _Float16* __restrict__ B3ih, _Float16* __restrict__ B3hh,
    _Float16* __restrict__ Ihi, _Float16* __restrict__ Ilo,
    _Float16* __restrict__ Hhi, _Float16* __restrict__ Hlo,
    float* __restrict__ flagcol, int* __restrict__ list0, int* __restrict__ counts,
    float* __restrict__ halt_accum, float* __restrict__ tot_rem) {
    size_t idx = (size_t)blockIdx.x * 256 + threadIdx.x;   // grid 16384 -> 4M
    {   // split inputs -> I, hidden -> H
        float x = inputs[idx];
        _Float16 h = f16hi(x);
        Ihi[idx] = h; Ilo[idx] = (_Float16)(x - (float)h);
        float y = hidden[idx];
        _Float16 g = f16hi(y);
        Hhi[idx] = g; Hlo[idx] = (_Float16)(y - (float)g);
    }
    if (idx < (size_t)KDIM * KDIM) {
        int n = (int)(idx >> 10), k = (int)(idx & 1023);
        float w = W_hh[idx];
        _Float16 hi = f16hi(w);
        _Float16 lo = (_Float16)(w - (float)hi);
        size_t base = (size_t)n * KV;
        B3hh[base + k] = hi; B3hh[base + 1024 + k] = lo; B3hh[base + 2048 + k] = hi;
        float w2 = W_ih[(size_t)n * 1025 + k];
        _Float16 hi2 = f16hi(w2);
        _Float16 lo2 = (_Float16)(w2 - (float)hi2);
        B3ih[base + k] = hi2; B3ih[base + 1024 + k] = lo2; B3ih[base + 2048 + k] = hi2;
    }
    if (idx < BATCH) { list0[idx] = idx; halt_accum[idx] = 0.f; tot_rem[idx] = 0.f; }
    if (idx < KDIM) flagcol[idx] = W_ih[idx * 1025 + 1024];
    if (idx < 16) counts[idx] = (idx == 0) ? BATCH : 0;
}

// mode 0: xout[row] = A @ B^T + bias (fp32)
// mode 1 full: h = tanh(acc + xbase + flag*flagcol + bias); store h + hi/lo f16
// tail (count < TAILTHRESH): write raw partial acc to psplit[bz][grd][c]
__global__ __launch_bounds__(256) void mfma_step_kernel(
    const _Float16* __restrict__ Ahi, const _Float16* __restrict__ Alo,
    const _Float16* __restrict__ B3, const float* __restrict__ bias,
    const float* __restrict__ xbase, const float* __restrict__ flagcol, float flag,
    const int* __restrict__ list, const int* __restrict__ pcount,
    float* __restrict__ hout, _Float16* __restrict__ houthi, _Float16* __restrict__ houtlo,
    float* __restrict__ xout, float* __restrict__ psplit, int mode) {
    int count = pcount ? *pcount : BATCH;
    bool tail = (count < TAILTHRESH);
    int bz = blockIdx.z;
    if (!tail && bz != 0) return;            // full path: z=0 only (R0 grid)
    int row0 = blockIdx.x * TMM;
    if (row0 >= count) return;
    int col0 = blockIdx.y * TNN;
    int c0 = tail ? bz * CPB : 0;            // chunk range [c0, c1)
    int c1 = tail ? c0 + CPB : NCHUNK;

    __shared__ _Float16 Asm[2][TMM][LDAH];
    __shared__ _Float16 Bsm[2][TNN][LDAH];

    int t = threadIdx.x;
    int lane = t & 63, w = t >> 6;
    int wm = (w & 1) * 64, wn = (w >> 1) * 32;

    // A staging: 128 rows x 8 half8-quads = 1024 quads, 4/thread (gathered rows)
    int arw[4], aq8[4]; size_t aoff[4];
#pragma unroll
    for (int l = 0; l < 4; l++) {
        int q = t + l * 256;
        int r = q >> 3, qk = q & 7;
        arw[l] = r; aq8[l] = qk * 8;
        int rr = row0 + r;
        int g = (rr < count) ? (list ? list[rr] : rr) : 0;
        aoff[l] = (size_t)g * KDIM + qk * 8;
    }
    // B staging: 64 n-rows x 8 quads = 512 quads, 2/thread
    int brw[2], bq8[2]; size_t boff[2];
#pragma unroll
    for (int l = 0; l < 2; l++) {
        int q = t + l * 256;
        int r = q >> 3, qk = q & 7;
        brw[l] = r; bq8[l] = qk * 8;
        boff[l] = (size_t)(col0 + r) * KV + qk * 8;
    }

    floatx4 acc[4][2];
#pragma unroll
    for (int i = 0; i < 4; i++)
#pragma unroll
        for (int j = 0; j < 2; j++) acc[i][j] = (floatx4)(0.f);

    int l15 = lane & 15, l4 = lane >> 4;

    // preload chunk c0 into buf 0
    half8 av[4], bv[2];
    {
        int k0v0 = c0 << 6;
        const _Float16* As0 = (k0v0 < 2048) ? Ahi : Alo;
        int kp0 = k0v0 & 1023;
#pragma unroll
        for (int l = 0; l < 4; l++) av[l] = *(const half8*)(As0 + aoff[l] + kp0);
#pragma unroll
        for (int l = 0; l < 2; l++) bv[l] = *(const half8*)(B3 + boff[l] + k0v0);
    }
#pragma unroll
    for (int l = 0; l < 4; l++) *(half8*)(&Asm[0][arw[l]][aq8[l]]) = av[l];
#pragma unroll
    for (int l = 0; l < 2; l++) *(half8*)(&Bsm[0][brw[l]][bq8[l]]) = bv[l];
    __syncthreads();

    int p = 0;
    for (int it = c0; it < c1; it++) {
        // issue global prefetch for chunk it+1 (overlaps with MFMA below)
        if (it + 1 < c1) {
            int k0v = (it + 1) << 6;
            const _Float16* Asrc = (k0v < 2048) ? Ahi : Alo;   // segs [hi,hi,lo]
            int kp = k0v & 1023;
#pragma unroll
            for (int l = 0; l < 4; l++) av[l] = *(const half8*)(Asrc + aoff[l] + kp);
#pragma unroll
            for (int l = 0; l < 2; l++) bv[l] = *(const half8*)(B3 + boff[l] + k0v);
        }
        // MFMA from buf p
#pragma unroll
        for (int ks = 0; ks < 2; ks++) {
            int ko = ks * 32 + l4 * 8;
            half8 af[4], bf[2];
#pragma unroll
            for (int fi = 0; fi < 4; fi++)
                af[fi] = *(const half8*)(&Asm[p][wm + fi * 16 + l15][ko]);
#pragma unroll
            for (int fj = 0; fj < 2; fj++)
                bf[fj] = *(const half8*)(&Bsm[p][wn + fj * 16 + l15][ko]);
#pragma unroll
            for (int fi = 0; fi < 4; fi++)
#pragma unroll
                for (int fj = 0; fj < 2; fj++)
                    acc[fi][fj] = __builtin_amdgcn_mfma_f32_16x16x32_f16(
                        af[fi], bf[fj], acc[fi][fj], 0, 0, 0);
        }
        // write prefetch to buf p^1
        if (it + 1 < c1) {
            int q = p ^ 1;
#pragma unroll
            for (int l = 0; l < 4; l++) *(half8*)(&Asm[q][arw[l]][aq8[l]]) = av[l];
#pragma unroll
            for (int l = 0; l < 2; l++) *(half8*)(&Bsm[q][brw[l]][bq8[l]]) = bv[l];
        }
        __syncthreads();
        p ^= 1;
    }

    // epilogue: C/D layout col = lane&15, row = (lane>>4)*4 + reg  [m89-verified]
    float* pout = psplit + (size_t)bz * ((size_t)TAILTHRESH * KDIM);
#pragma unroll
    for (int fi = 0; fi < 4; fi++) {
#pragma unroll
        for (int rr = 0; rr < 4; rr++) {
            int lm = wm + fi * 16 + l4 * 4 + rr;
            int grd = row0 + lm;
            if (grd >= count) continue;
#pragma unroll
            for (int fj = 0; fj < 2; fj++) {
                int c = col0 + wn + fj * 16 + l15;
                float v = acc[fi][fj][rr];
                if (tail) {
                    pout[(size_t)grd * KDIM + c] = v;   // list-relative index
                } else {
                    int g = list ? list[grd] : grd;
                    if (mode == 0) {
                        xout[(size_t)g * KDIM + c] = v + bias[c];
                    } else {
                        v += xbase[(size_t)g * KDIM + c] + flag * flagcol[c] + bias[c];
                        v = tanhf(v);
                        hout[(size_t)g * KDIM + c] = v;
                        _Float16 hi = f16hi(v);
                        houthi[(size_t)g * KDIM + c] = hi;
                        houtlo[(size_t)g * KDIM + c] = (_Float16)(v - (float)hi);
                    }
                }
            }
        }
    }
}

// One wave per active row. Full path (count>=TAILTHRESH): as before, reads h.
// Tail path: fused combine — h = tanh(xbase + b_hh + sum of 4 partials),
// dot with W_halt, halting state machine, tot_h accum, hi/lo f16 store for
// the next step's A. h fp32 never materialized for tails.
__global__ __launch_bounds__(256) void halt_kernel(
    const float* __restrict__ h, const float* __restrict__ W_halt,
    const float* __restrict__ b_halt,
    const int* __restrict__ list, const int* __restrict__ pcount,
    int* __restrict__ list_next, int* __restrict__ pcount_next,
    float* __restrict__ halt_accum, float* __restrict__ tot_rem,
    float* __restrict__ tot_h, float* __restrict__ steps_out,
    int stepnum, int first,
    const float* __restrict__ xbase, const float* __restrict__ b_hh,
    const float* __restrict__ psplit,
    _Float16* __restrict__ houthi, _Float16* __restrict__ houtlo) {
    int count = *pcount;
    int wid = threadIdx.x >> 6, lane = threadIdx.x & 63;
    int r = blockIdx.x * 4 + wid;
    if (r >= count) return;
    int row = list[r];

    if (count < TAILTHRESH) {
        // ---------------- fused tail path ----------------
        const size_t PSTR = (size_t)TAILTHRESH * KDIM;
        const float* p0 = psplit;
        const float* p1 = psplit + PSTR;
        const float* p2 = psplit + 2 * PSTR;
        const float* p3 = psplit + 3 * PSTR;
        const float* xr = xbase + (size_t)row * HID;
        size_t rb = (size_t)r * KDIM;           // list-relative partial base
        size_t gb = (size_t)row * HID;          // global row base
        float4 hv[4];
        float dot = 0.f;
#pragma unroll
        for (int q = 0; q < 4; q++) {
            int c = q * 256 + lane * 4;
            float4 x = *(const float4*)(xr + c);
            float4 bb = *(const float4*)(b_hh + c);
            float4 s0 = *(const float4*)(p0 + rb + c);
            float4 s1 = *(const float4*)(p1 + rb + c);
            float4 s2 = *(const float4*)(p2 + rb + c);
            float4 s3 = *(const float4*)(p3 + rb + c);
            float4 hh;
            hh.x = tanhf(x.x + bb.x + s0.x + s1.x + s2.x + s3.x);
            hh.y = tanhf(x.y + bb.y + s0.y + s1.y + s2.y + s3.y);
            hh.z = tanhf(x.z + bb.z + s0.z + s1.z + s2.z + s3.z);
            hh.w = tanhf(x.w + bb.w + s0.w + s1.w + s2.w + s3.w);
            hv[q] = hh;
            float4 wv = *(const float4*)(W_halt + c);
            dot += hh.x * wv.x + hh.y * wv.y + hh.z * wv.z + hh.w * wv.w;
            half4v hi4, lo4;
            hi4[0] = f16hi(hh.x); lo4[0] = (_Float16)(hh.x - (float)hi4[0]);
            hi4[1] = f16hi(hh.y); lo4[1] = (_Float16)(hh.y - (float)hi4[1]);
            hi4[2] = f16hi(hh.z); lo4[2] = (_Float16)(hh.z - (float)hi4[2]);
            hi4[3] = f16hi(hh.w); lo4[3] = (_Float16)(hh.w - (float)hi4[3]);
            *(half4v*)(houthi + gb + c) = hi4;
            *(half4v*)(houtlo + gb + c) = lo4;
        }
#pragma unroll
        for (int off = 32; off > 0; off >>= 1) dot += __shfl_down(dot, off);

        float combined = 0.f;
        if (lane == 0) {
            float p = 1.f / (1.f + expf(-(dot + b_halt[0])));
            float S = halt_accum[row] + p;
            halt_accum[row] = S;
            tot_rem[row] += p;
            bool ending = (S + p) > 0.99f;
            if (ending) {
                combined = p + (1.f - S);
                steps_out[row] = (float)stepnum;
            } else {
                combined = p;
                int idx = atomicAdd(pcount_next, 1);
                list_next[idx] = row;
            }
        }
        combined = __shfl(combined, 0);

        float* th = tot_h + gb;
#pragma unroll
        for (int q = 0; q < 4; q++) {
            int c = q * 256 + lane * 4;
            float4 ov = *(const float4*)(th + c);   // tails always t>=1
            ov.x += combined * hv[q].x; ov.y += combined * hv[q].y;
            ov.z += combined * hv[q].z; ov.w += combined * hv[q].w;
            *(float4*)(th + c) = ov;
        }
        return;
    }

    // ---------------- full path (R1-verified) ----------------
    const float* hr = h + (size_t)row * HID;
    float dot = 0.f;
#pragma unroll
    for (int q = 0; q < 4; q++) {
        int c = q * 256 + lane * 4;
        float4 hvv = *(const float4*)(hr + c);
        float4 wv = *(const float4*)(W_halt + c);
        dot += hvv.x * wv.x + hvv.y * wv.y + hvv.z * wv.z + hvv.w * wv.w;
    }
#pragma unroll
    for (int off = 32; off > 0; off >>= 1) dot += __shfl_down(dot, off);

    float combined = 0.f;
    if (lane == 0) {
        float p = 1.f / (1.f + expf(-(dot + b_halt[0])));
        float S = halt_accum[row] + p;
        halt_accum[row] = S;
        tot_rem[row] += p;
        bool ending = (S + p) > 0.99f;      // budget = 1 - PONDER_EPS
        if (ending) {
            combined = p + (1.f - S);
            steps_out[row] = (float)stepnum;
        } else {
            combined = p;
            int idx = atomicAdd(pcount_next, 1);
            list_next[idx] = row;
        }
    }
    combined = __shfl(combined, 0);

    float* th = tot_h + (size_t)row * HID;
#pragma unroll
    for (int q = 0; q < 4; q++) {
        int c = q * 256 + lane * 4;
        float4 hvv = *(const float4*)(hr + c);
        float4 ov;
        if (first) {
            ov.x = combined * hvv.x; ov.y = combined * hvv.y;
            ov.z = combined * hvv.z; ov.w = combined * hvv.w;
        } else {
            ov = *(const float4*)(th + c);
            ov.x += combined * hvv.x; ov.y += combined * hvv.y;
            ov.z += combined * hvv.z; ov.w += combined * hvv.w;
        }
        *(float4*)(th + c) = ov;
    }
}

// blocks 0..1023: survivors get (1 - halt_accum) * h_final, steps = 16.
// h reconstructed from final hi/lo f16 buffers (valid for both paths).
// block 1024: ponder reduction.
__global__ __launch_bounds__(256) void epilogue_kernel(
    const _Float16* __restrict__ hhi, const _Float16* __restrict__ hlo,
    const int* __restrict__ list,
    const int* __restrict__ pcount, const float* __restrict__ halt_accum,
    const float* __restrict__ tot_rem,
    float* __restrict__ tot_h, float* __restrict__ steps_out,
    float* __restrict__ ponder) {
    if (blockIdx.x == 1024) {
        __shared__ float red[4];
        int t = threadIdx.x;
        float v = 0.f;
#pragma unroll
        for (int i = 0; i < 16; i++) v += tot_rem[t + i * 256];
#pragma unroll
        for (int off = 32; off > 0; off >>= 1) v += __shfl_down(v, off);
        int lane = t & 63, wid = t >> 6;
        if (lane == 0) red[wid] = v;
        __syncthreads();
        if (t == 0) ponder[0] = (red[0] + red[1] + red[2] + red[3]) * (-0.01f / 4096.f);
        return;
    }
    int count = *pcount;
    int wid = threadIdx.x >> 6, lane = threadIdx.x & 63;
    int r = blockIdx.x * 4 + wid;
    if (r >= count) return;
    int row = list[r];
    float cmb = 1.f - halt_accum[row];
    if (lane == 0) steps_out[row] = 16.f;
    const _Float16* hih = hhi + (size_t)row * HID;
    const _Float16* loh = hlo + (size_t)row * HID;
    float* th = tot_h + (size_t)row * HID;
#pragma unroll
    for (int q = 0; q < 4; q++) {
        int c = q * 256 + lane * 4;
        half4v hi4 = *(const half4v*)(hih + c);
        half4v lo4 = *(const half4v*)(loh + c);
        float4 ov = *(const float4*)(th + c);
        ov.x += cmb * ((float)hi4[0] + (float)lo4[0]);
        ov.y += cmb * ((float)hi4[1] + (float)lo4[1]);
        ov.z += cmb * ((float)hi4[2] + (float)lo4[2]);
        ov.w += cmb * ((float)hi4[3] + (float)lo4[3]);
        *(float4*)(th + c) = ov;
    }
}

extern "C" void kernel_launch(void* const* d_in, const int* in_sizes, int n_in,
                              void* d_out, int out_size, void* d_ws, size_t ws_size,
                              hipStream_t stream) {
    const float* inputs = (const float*)d_in[0];
    const float* hidden = (const float*)d_in[1];
    const float* W_ih   = (const float*)d_in[2];
    const float* b_ih   = (const float*)d_in[3];
    const float* W_hh   = (const float*)d_in[4];
    const float* b_hh   = (const float*)d_in[5];
    const float* W_halt = (const float*)d_in[6];
    const float* b_halt = (const float*)d_in[7];
    float* out = (float*)d_out;

    float* ws = (float*)d_ws;
    const size_t NM = (size_t)BATCH * HID;               // 4M
    float* xbase = ws;                                   // 4M f32
    float* h     = xbase + NM;                           // 4M f32
    _Float16* B3ih = (_Float16*)(h + NM);                // 1024*3072 halfs
    _Float16* B3hh = B3ih + (size_t)HID * KV;
    _Float16* Ahi0 = B3hh + (size_t)HID * KV;            // 4M halfs each
    _Float16* Alo0 = Ahi0 + NM;
    _Float16* Ahi1 = Alo0 + NM;
    _Float16* Alo1 = Ahi1 + NM;
    float* flagcol = (float*)(Alo1 + NM);                // 1024
    float* halt_accum = flagcol + KDIM;                  // 4096
    float* tot_rem = halt_accum + BATCH;                 // 4096
    int* list0 = (int*)(tot_rem + BATCH);                // 4096
    int* list1 = list0 + BATCH;                          // 4096
    int* counts = list1 + BATCH;                         // 16
    float* psplit = (float*)(counts + 16);               // 4 x 2048*1024 f32 (32MB)

    _Float16* Ahi[2] = {Ahi0, Ahi1};
    _Float16* Alo[2] = {Alo0, Alo1};
    int* lists[2] = {list0, list1};

    float* tot_h = out;
    float* ponder = out + NM;
    float* steps_out = ponder + 1;

    // setup + split fused: inputs -> buf1 (dead after x_base), hidden -> buf0
    setup_kernel<<<16384, 256, 0, stream>>>(W_ih, W_hh, inputs, hidden,
                                            B3ih, B3hh, Ahi1, Alo1, Ahi0, Alo0,
                                            flagcol, list0, counts, halt_accum, tot_rem);

    // x_base = inputs @ W_ih[:, :-1].T + b_ih   (full path: count = BATCH)
    mfma_step_kernel<<<dim3(32, 16, SKT), 256, 0, stream>>>(
        Ahi1, Alo1, B3ih, b_ih, nullptr, nullptr, 0.f, nullptr, nullptr,
        nullptr, nullptr, nullptr, xbase, psplit, 0);

    for (int t = 0; t < NSTEP; t++) {
        mfma_step_kernel<<<dim3(32, 16, SKT), 256, 0, stream>>>(
            Ahi[t & 1], Alo[t & 1], B3hh, b_hh, xbase, flagcol,
            (t == 0) ? 1.f : 0.f, lists[t & 1], counts + t,
            h, Ahi[(t + 1) & 1], Alo[(t + 1) & 1], nullptr, psplit, 1);
        halt_kernel<<<1024, 256, 0, stream>>>(h, W_halt, b_halt,
                                              lists[t & 1], counts + t,
                                              lists[(t + 1) & 1], counts + t + 1,
                                              halt_accum, tot_rem, tot_h, steps_out,
                                              t + 1, (t == 0) ? 1 : 0,
                                              xbase, b_hh, psplit,
                                              Ahi[(t + 1) & 1], Alo[(t + 1) & 1]);
    }
    epilogue_kernel<<<1025, 256, 0, stream>>>(Ahi[1], Alo[1], lists[1], counts + 15,
                                              halt_accum, tot_rem, tot_h, steps_out, ponder);
}